// Round 1
// baseline (913.856 us; speedup 1.0000x reference)
//
#include <hip/hip_runtime.h>

#define E_EDGES 320000
#define NSENT   100000
#define NSENT_P 100096
#define NSECT   20000
#define NSECT_P 20096
#define SDIM    256
#define TDIM    512
#define FFN     2048

typedef short bf16x8 __attribute__((ext_vector_type(8)));
typedef float f32x4  __attribute__((ext_vector_type(4)));

static __device__ __forceinline__ float bf2f(unsigned short u) {
    unsigned int i = ((unsigned int)u) << 16;
    float f; __builtin_memcpy(&f, &i, 4); return f;
}
static __device__ __forceinline__ unsigned short f2bf(float f) {
    unsigned int i; __builtin_memcpy(&i, &f, 4);
    unsigned int r = i + 0x7FFFu + ((i >> 16) & 1u);
    return (unsigned short)(r >> 16);
}

// ---------------- fold: W[K,512] x a[8,64] -> Wf[K,8] -------------------
__global__ void k_fold(const float* __restrict__ W1s, const float* __restrict__ al1,
                       const float* __restrict__ W1d, const float* __restrict__ ar1,
                       const float* __restrict__ W2,  const float* __restrict__ al2,
                       const float* __restrict__ ar2,
                       float* __restrict__ Wl1, float* __restrict__ Wr1,
                       float* __restrict__ Wl2, float* __restrict__ Wr2)
{
    int t = blockIdx.x * 256 + threadIdx.x;
    const float* W; const float* a; float* o; int rel;
    if      (t < 2048)  { W = W1s; a = al1; o = Wl1; rel = t; }
    else if (t < 6144)  { W = W1d; a = ar1; o = Wr1; rel = t - 2048; }
    else if (t < 10240) { W = W2;  a = al2; o = Wl2; rel = t - 6144; }
    else if (t < 14336) { W = W2;  a = ar2; o = Wr2; rel = t - 10240; }
    else return;
    int k = rel >> 3, h = rel & 7;
    float s = 0.f;
    for (int d = 0; d < 64; ++d) s += W[k * 512 + h * 64 + d] * a[h * 64 + d];
    o[rel] = s;
}

// ---------------- transpose f32[R,C] -> bf16[C,R] -----------------------
__global__ void k_transpose(const float* __restrict__ in, unsigned short* __restrict__ out,
                            int R, int C)
{
    __shared__ float tile[32][33];
    int c0 = blockIdx.x * 32, r0 = blockIdx.y * 32;
    int tx = threadIdx.x, ty = threadIdx.y;
#pragma unroll
    for (int i = 0; i < 4; ++i)
        tile[ty + i * 8][tx] = in[(long)(r0 + ty + i * 8) * C + c0 + tx];
    __syncthreads();
#pragma unroll
    for (int i = 0; i < 4; ++i)
        out[(long)(c0 + ty + i * 8) * R + r0 + tx] = f2bf(tile[tx][ty + i * 8]);
}

// ---------------- convert f32 -> bf16 with zero row padding -------------
__global__ void k_convert_pad(const float* __restrict__ X, unsigned short* __restrict__ out,
                              int Nreal, int Npad, int Cc)
{
    long i4 = ((long)blockIdx.x * 256 + threadIdx.x) * 4;
    if (i4 >= (long)Npad * Cc) return;
    int row = (int)(i4 / Cc);
    uint2 o;
    if (row < Nreal) {
        float4 v = *(const float4*)(X + i4);
        o.x = ((unsigned int)f2bf(v.x)) | (((unsigned int)f2bf(v.y)) << 16);
        o.y = ((unsigned int)f2bf(v.z)) | (((unsigned int)f2bf(v.w)) << 16);
    } else { o.x = 0u; o.y = 0u; }
    *(uint2*)(out + i4) = o;
}

// ---------------- attention projection: out[N,8] = X[N,K] @ W[K,8] ------
__global__ void k_attproj(const float* __restrict__ X, const float* __restrict__ W,
                          float* __restrict__ out, int Nrows, int K)
{
    int t = blockIdx.x * 256 + threadIdx.x;
    if (t >= Nrows * 8) return;
    int row = t >> 3, h = t & 7;
    const float* x = X + (long)row * K;
    float s = 0.f;
    for (int k = 0; k < K; ++k) s += x[k] * W[k * 8 + h];
    out[t] = s;
}

// ---------------- MFMA GEMM: C[M,N] = A[M,K]bf16 @ BT[N,K]bf16 ----------
// EPI 0: store bf16  | 1: +bias, relu, store bf16 | 2: +bias, store f32 (row<Mreal)
template<int EPI>
__global__ __launch_bounds__(256)
void k_gemm(const unsigned short* __restrict__ A, const unsigned short* __restrict__ BT,
            void* __restrict__ C, const float* __restrict__ bias,
            int N, int K, int Mreal)
{
    __shared__ unsigned short a_s[128][40];
    __shared__ unsigned short b_s[128][40];
    const int tid  = threadIdx.x;
    const int lane = tid & 63;
    const int wid  = tid >> 6;
    const int wr   = (wid >> 1) * 64;
    const int wc   = (wid & 1) * 64;
    const int row0 = blockIdx.x * 128;
    const int col0 = blockIdx.y * 128;
    const int sr   = tid >> 2;
    const int sc   = (tid & 3) * 8;

    f32x4 acc[4][4] = {};

    const unsigned short* pa0 = A + (long)(row0 + sr) * K + sc;
    const unsigned short* pa1 = pa0 + (long)64 * K;
    const unsigned short* pb0 = BT + (long)(col0 + sr) * K + sc;
    const unsigned short* pb1 = pb0 + (long)64 * K;

    for (int k0 = 0; k0 < K; k0 += 32) {
        uint4 va0 = *(const uint4*)(pa0 + k0);
        uint4 va1 = *(const uint4*)(pa1 + k0);
        uint4 vb0 = *(const uint4*)(pb0 + k0);
        uint4 vb1 = *(const uint4*)(pb1 + k0);
        __syncthreads();
        *(uint4*)&a_s[sr][sc]      = va0;
        *(uint4*)&a_s[sr + 64][sc] = va1;
        *(uint4*)&b_s[sr][sc]      = vb0;
        *(uint4*)&b_s[sr + 64][sc] = vb1;
        __syncthreads();
        bf16x8 af[4], bfr[4];
#pragma unroll
        for (int m = 0; m < 4; ++m)
            af[m] = *(const bf16x8*)&a_s[wr + m * 16 + (lane & 15)][8 * (lane >> 4)];
#pragma unroll
        for (int n = 0; n < 4; ++n)
            bfr[n] = *(const bf16x8*)&b_s[wc + n * 16 + (lane & 15)][8 * (lane >> 4)];
#pragma unroll
        for (int m = 0; m < 4; ++m)
#pragma unroll
            for (int n = 0; n < 4; ++n)
                acc[m][n] = __builtin_amdgcn_mfma_f32_16x16x32_bf16(af[m], bfr[n], acc[m][n], 0, 0, 0);
    }

#pragma unroll
    for (int m = 0; m < 4; ++m) {
        int row_t = wr + m * 16 + ((lane >> 4) << 2);
#pragma unroll
        for (int n = 0; n < 4; ++n) {
            int col = col0 + wc + n * 16 + (lane & 15);
#pragma unroll
            for (int r = 0; r < 4; ++r) {
                int row = row0 + row_t + r;
                float v = acc[m][n][r];
                if (EPI >= 1) v += bias[col];
                if (EPI == 1) v = fmaxf(v, 0.f);
                if (EPI <= 1) {
                    ((unsigned short*)C)[(long)row * N + col] = f2bf(v);
                } else {
                    if (row < Mreal) ((float*)C)[(long)row * N + col] = v;
                }
            }
        }
    }
}

// ---------------- CSR build ---------------------------------------------
__global__ void k_hist(const int* __restrict__ dst, int* __restrict__ cnt, int E)
{
    int i = blockIdx.x * 256 + threadIdx.x;
    if (i < E) atomicAdd(&cnt[dst[i]], 1);
}

__global__ void k_scan(const int* __restrict__ cnt, int* __restrict__ off,
                       int* __restrict__ cur, int Nseg)
{
    __shared__ int partial[1024];
    int t = threadIdx.x;
    int chunk = (Nseg + 1023) / 1024;
    int b = t * chunk;
    int e_ = b + chunk; if (e_ > Nseg) e_ = Nseg; if (b > Nseg) b = Nseg;
    int s = 0;
    for (int i = b; i < e_; ++i) s += cnt[i];
    partial[t] = s;
    __syncthreads();
    for (int d = 1; d < 1024; d <<= 1) {
        int v = partial[t];
        int w = (t >= d) ? partial[t - d] : 0;
        __syncthreads();
        partial[t] = v + w;
        __syncthreads();
    }
    int run = (t == 0) ? 0 : partial[t - 1];
    for (int i = b; i < e_; ++i) { off[i] = run; cur[i] = run; run += cnt[i]; }
    if (t == 1023) off[Nseg] = partial[1023];
}

__global__ void k_scatter(const int* __restrict__ src, const int* __restrict__ dst,
                          int* __restrict__ cur, int* __restrict__ srcs, int E)
{
    int i = blockIdx.x * 256 + threadIdx.x;
    if (i < E) {
        int p = atomicAdd(&cur[dst[i]], 1);
        srcs[p] = src[i];
    }
}

// ---------------- GAT aggregation: one wave per dst segment -------------
__global__ __launch_bounds__(256)
void k_aggregate(const unsigned short* __restrict__ fs, const float* __restrict__ el,
                 const float* __restrict__ er, const float* __restrict__ bias,
                 const int* __restrict__ off, const int* __restrict__ srcs,
                 float* __restrict__ out, int Ndst)
{
    int n = blockIdx.x * 4 + (threadIdx.x >> 6);
    if (n >= Ndst) return;
    int lane = threadIdx.x & 63;
    int h8 = lane & 7;
    int beg = off[n], end = off[n + 1];
    float er_h = er[n * 8 + h8];

    float mx = -3.0e38f;
    for (int p = beg + (lane >> 3); p < end; p += 8) {
        int s = srcs[p];
        float e = el[s * 8 + h8] + er_h;
        e = (e >= 0.f) ? e : 0.2f * e;
        mx = fmaxf(mx, e);
    }
    mx = fmaxf(mx, __shfl_xor(mx, 8));
    mx = fmaxf(mx, __shfl_xor(mx, 16));
    mx = fmaxf(mx, __shfl_xor(mx, 32));

    float dsum = 0.f;
    for (int p = beg + (lane >> 3); p < end; p += 8) {
        int s = srcs[p];
        float e = el[s * 8 + h8] + er_h;
        e = (e >= 0.f) ? e : 0.2f * e;
        dsum += __expf(e - mx);
    }
    dsum += __shfl_xor(dsum, 8);
    dsum += __shfl_xor(dsum, 16);
    dsum += __shfl_xor(dsum, 32);

    int hc = lane >> 3;                 // head owned by this lane's 8 dims
    float mx_c   = __shfl(mx, hc);
    float dsum_c = __shfl(dsum, hc);
    float er_c   = er[n * 8 + hc];

    float a0=0,a1=0,a2=0,a3=0,a4=0,a5=0,a6=0,a7=0;
    const unsigned short* fsl = fs + lane * 8;
    for (int p = beg; p < end; ++p) {
        int s = srcs[p];
        float e = el[s * 8 + hc] + er_c;
        e = (e >= 0.f) ? e : 0.2f * e;
        float w = __expf(e - mx_c);
        uint4 v = *(const uint4*)(fsl + (long)s * 512);
        a0 += w * bf2f((unsigned short)(v.x & 0xFFFF));
        a1 += w * bf2f((unsigned short)(v.x >> 16));
        a2 += w * bf2f((unsigned short)(v.y & 0xFFFF));
        a3 += w * bf2f((unsigned short)(v.y >> 16));
        a4 += w * bf2f((unsigned short)(v.z & 0xFFFF));
        a5 += w * bf2f((unsigned short)(v.z >> 16));
        a6 += w * bf2f((unsigned short)(v.w & 0xFFFF));
        a7 += w * bf2f((unsigned short)(v.w >> 16));
    }
    float inv = 1.f / fmaxf(dsum_c, 1e-9f);
    const float* bp = bias + lane * 8;
    float o[8] = { a0*inv + bp[0], a1*inv + bp[1], a2*inv + bp[2], a3*inv + bp[3],
                   a4*inv + bp[4], a5*inv + bp[5], a6*inv + bp[6], a7*inv + bp[7] };
#pragma unroll
    for (int j = 0; j < 8; ++j) o[j] = (o[j] > 0.f) ? o[j] : (__expf(o[j]) - 1.f);
    float4 w0 = make_float4(o[0], o[1], o[2], o[3]);
    float4 w1 = make_float4(o[4], o[5], o[6], o[7]);
    *(float4*)(out + (long)n * 512 + lane * 8)     = w0;
    *(float4*)(out + (long)n * 512 + lane * 8 + 4) = w1;
}

// ---------------- fusion gate + residual -> bf16 h ----------------------
__global__ __launch_bounds__(256)
void k_fusion(const float* __restrict__ sect, const float* __restrict__ s2S,
              const float* __restrict__ S2S, const float* __restrict__ fw,
              const float* __restrict__ fb, unsigned short* __restrict__ hout)
{
    int n = blockIdx.x * 4 + (threadIdx.x >> 6);
    if (n >= NSECT_P) return;
    int lane = threadIdx.x & 63;
    unsigned short* op = hout + (long)n * TDIM + lane * 8;
    if (n >= NSECT) {
        uint4 z = make_uint4(0u, 0u, 0u, 0u);
        *(uint4*)op = z;
        return;
    }
    long base = (long)n * TDIM + lane * 8;
    float4 p0 = *(const float4*)(s2S + base);
    float4 p1 = *(const float4*)(s2S + base + 4);
    float4 q0 = *(const float4*)(S2S + base);
    float4 q1 = *(const float4*)(S2S + base + 4);
    float4 wa0 = *(const float4*)(fw + lane * 8);
    float4 wa1 = *(const float4*)(fw + lane * 8 + 4);
    float4 wb0 = *(const float4*)(fw + 512 + lane * 8);
    float4 wb1 = *(const float4*)(fw + 512 + lane * 8 + 4);
    float part = p0.x*wa0.x + p0.y*wa0.y + p0.z*wa0.z + p0.w*wa0.w
               + p1.x*wa1.x + p1.y*wa1.y + p1.z*wa1.z + p1.w*wa1.w
               + q0.x*wb0.x + q0.y*wb0.y + q0.z*wb0.z + q0.w*wb0.w
               + q1.x*wb1.x + q1.y*wb1.y + q1.z*wb1.z + q1.w*wb1.w;
#pragma unroll
    for (int s = 1; s < 64; s <<= 1) part += __shfl_xor(part, s);
    float z = 1.f / (1.f + __expf(-(part + fb[0])));
    float4 r0 = *(const float4*)(sect + base);
    float4 r1 = *(const float4*)(sect + base + 4);
    float h[8];
    h[0] = r0.x + z * p0.x + (1.f - z) * q0.x;
    h[1] = r0.y + z * p0.y + (1.f - z) * q0.y;
    h[2] = r0.z + z * p0.z + (1.f - z) * q0.z;
    h[3] = r0.w + z * p0.w + (1.f - z) * q0.w;
    h[4] = r1.x + z * p1.x + (1.f - z) * q1.x;
    h[5] = r1.y + z * p1.y + (1.f - z) * q1.y;
    h[6] = r1.z + z * p1.z + (1.f - z) * q1.z;
    h[7] = r1.w + z * p1.w + (1.f - z) * q1.w;
    uint4 o;
    o.x = ((unsigned int)f2bf(h[0])) | (((unsigned int)f2bf(h[1])) << 16);
    o.y = ((unsigned int)f2bf(h[2])) | (((unsigned int)f2bf(h[3])) << 16);
    o.z = ((unsigned int)f2bf(h[4])) | (((unsigned int)f2bf(h[5])) << 16);
    o.w = ((unsigned int)f2bf(h[6])) | (((unsigned int)f2bf(h[7])) << 16);
    *(uint4*)op = o;
}

// ------------------------------------------------------------------------
extern "C" void kernel_launch(void* const* d_in, const int* in_sizes, int n_in,
                              void* d_out, int out_size, void* d_ws, size_t ws_size,
                              hipStream_t stream)
{
    (void)in_sizes; (void)n_in; (void)out_size; (void)ws_size;
    const float* sent    = (const float*)d_in[0];
    const float* sect    = (const float*)d_in[1];
    const int*   s2S_src = (const int*)d_in[2];
    const int*   s2S_dst = (const int*)d_in[3];
    const int*   S2S_src = (const int*)d_in[4];
    const int*   S2S_dst = (const int*)d_in[5];
    const float* W1_src  = (const float*)d_in[6];
    const float* W1_dst  = (const float*)d_in[7];
    const float* al1     = (const float*)d_in[8];
    const float* ar1     = (const float*)d_in[9];
    const float* b1      = (const float*)d_in[10];
    const float* W2      = (const float*)d_in[11];
    const float* al2     = (const float*)d_in[12];
    const float* ar2     = (const float*)d_in[13];
    const float* b2      = (const float*)d_in[14];
    const float* fus_w   = (const float*)d_in[15];
    const float* fus_b   = (const float*)d_in[16];
    const float* ffn_w1  = (const float*)d_in[17];
    const float* ffn_b1  = (const float*)d_in[18];
    const float* ffn_w2  = (const float*)d_in[19];
    const float* ffn_b2  = (const float*)d_in[20];

    char* ws = (char*)d_ws;
    size_t curo = 0;
    auto alloc = [&](size_t sz) -> void* {
        void* p = ws + curo; curo += (sz + 255) & ~(size_t)255; return p;
    };

    unsigned short* sent_b = (unsigned short*)alloc((size_t)NSENT_P * SDIM * 2);
    unsigned short* sect_b = (unsigned short*)alloc((size_t)NSECT_P * TDIM * 2);
    unsigned short* w1t    = (unsigned short*)alloc((size_t)512 * 256 * 2);
    unsigned short* w2t    = (unsigned short*)alloc((size_t)512 * 512 * 2);
    unsigned short* fw1t   = (unsigned short*)alloc((size_t)2048 * 512 * 2);
    unsigned short* fw2t   = (unsigned short*)alloc((size_t)512 * 2048 * 2);
    float* Wl1 = (float*)alloc(256 * 8 * 4);
    float* Wr1 = (float*)alloc(512 * 8 * 4);
    float* Wl2 = (float*)alloc(512 * 8 * 4);
    float* Wr2 = (float*)alloc(512 * 8 * 4);
    float* el1 = (float*)alloc((size_t)NSENT * 8 * 4);
    float* er1 = (float*)alloc((size_t)NSECT * 8 * 4);
    float* el2 = (float*)alloc((size_t)NSECT * 8 * 4);
    float* er2 = (float*)alloc((size_t)NSECT * 8 * 4);
    unsigned short* fs1 = (unsigned short*)alloc((size_t)NSENT_P * 512 * 2);
    unsigned short* f2  = (unsigned short*)alloc((size_t)NSECT_P * 512 * 2);
    int* cnt1 = (int*)alloc((size_t)NSECT * 4);
    int* cnt2 = (int*)alloc((size_t)NSECT * 4);
    int* off1 = (int*)alloc((size_t)(NSECT + 1) * 4);
    int* off2 = (int*)alloc((size_t)(NSECT + 1) * 4);
    int* cur1 = (int*)alloc((size_t)NSECT * 4);
    int* cur2 = (int*)alloc((size_t)NSECT * 4);
    int* srcs1 = (int*)alloc((size_t)E_EDGES * 4);
    int* srcs2 = (int*)alloc((size_t)E_EDGES * 4);
    float* s2Sb = (float*)alloc((size_t)NSECT * 512 * 4);
    float* S2Sb = (float*)alloc((size_t)NSECT * 512 * 4);
    unsigned short* hb = (unsigned short*)alloc((size_t)NSECT_P * TDIM * 2);
    unsigned short* tb = fs1;   // alias: t[20096,2048] bf16 (82.3MB) over fs1 (102.5MB), fs1 dead by then

    // 1. folds + weight transposes + input converts + att projections
    k_fold<<<56, 256, 0, stream>>>(W1_src, al1, W1_dst, ar1, W2, al2, ar2, Wl1, Wr1, Wl2, Wr2);
    k_transpose<<<dim3(16, 8),  dim3(32, 8), 0, stream>>>(W1_src, w1t, 256, 512);
    k_transpose<<<dim3(16, 16), dim3(32, 8), 0, stream>>>(W2,     w2t, 512, 512);
    k_transpose<<<dim3(64, 16), dim3(32, 8), 0, stream>>>(ffn_w1, fw1t, 512, 2048);
    k_transpose<<<dim3(16, 64), dim3(32, 8), 0, stream>>>(ffn_w2, fw2t, 2048, 512);
    k_convert_pad<<<(NSENT_P * SDIM / 4 + 255) / 256, 256, 0, stream>>>(sent, sent_b, NSENT, NSENT_P, SDIM);
    k_convert_pad<<<(NSECT_P * TDIM / 4 + 255) / 256, 256, 0, stream>>>(sect, sect_b, NSECT, NSECT_P, TDIM);
    k_attproj<<<(NSENT * 8 + 255) / 256, 256, 0, stream>>>(sent, Wl1, el1, NSENT, SDIM);
    k_attproj<<<(NSECT * 8 + 255) / 256, 256, 0, stream>>>(sect, Wr1, er1, NSECT, TDIM);
    k_attproj<<<(NSECT * 8 + 255) / 256, 256, 0, stream>>>(sect, Wl2, el2, NSECT, TDIM);
    k_attproj<<<(NSECT * 8 + 255) / 256, 256, 0, stream>>>(sect, Wr2, er2, NSECT, TDIM);

    // 2. feature GEMMs
    k_gemm<0><<<dim3(NSENT_P / 128, 4), 256, 0, stream>>>(sent_b, w1t, fs1, nullptr, 512, 256, 0);
    k_gemm<0><<<dim3(NSECT_P / 128, 4), 256, 0, stream>>>(sect_b, w2t, f2,  nullptr, 512, 512, 0);

    // 3. CSR build
    hipMemsetAsync(cnt1, 0, (size_t)NSECT * 4, stream);
    hipMemsetAsync(cnt2, 0, (size_t)NSECT * 4, stream);
    k_hist<<<E_EDGES / 256, 256, 0, stream>>>(s2S_dst, cnt1, E_EDGES);
    k_hist<<<E_EDGES / 256, 256, 0, stream>>>(S2S_dst, cnt2, E_EDGES);
    k_scan<<<1, 1024, 0, stream>>>(cnt1, off1, cur1, NSECT);
    k_scan<<<1, 1024, 0, stream>>>(cnt2, off2, cur2, NSECT);
    k_scatter<<<E_EDGES / 256, 256, 0, stream>>>(s2S_src, s2S_dst, cur1, srcs1, E_EDGES);
    k_scatter<<<E_EDGES / 256, 256, 0, stream>>>(S2S_src, S2S_dst, cur2, srcs2, E_EDGES);

    // 4. aggregation (softmax-weighted messages + bias + ELU)
    k_aggregate<<<NSECT / 4, 256, 0, stream>>>(fs1, el1, er1, b1, off1, srcs1, s2Sb, NSECT);
    k_aggregate<<<NSECT / 4, 256, 0, stream>>>(f2,  el2, er2, b2, off2, srcs2, S2Sb, NSECT);

    // 5. fusion gate + residual
    k_fusion<<<NSECT_P / 4, 256, 0, stream>>>(sect, s2Sb, S2Sb, fus_w, fus_b, hb);

    // 6. FFN
    k_gemm<1><<<dim3(NSECT_P / 128, FFN / 128), 256, 0, stream>>>(hb, fw1t, tb, ffn_b1, FFN, 512, 0);
    k_gemm<2><<<dim3(NSECT_P / 128, 4), 256, 0, stream>>>(tb, fw2t, d_out, ffn_b2, 512, FFN, NSECT);
}

// Round 2
// 777.948 us; speedup vs baseline: 1.1747x; 1.1747x over previous
//
#include <hip/hip_runtime.h>

#define E_EDGES 320000
#define NSENT   100000
#define NSENT_P 100096
#define NSECT   20000
#define NSECT_P 20096
#define SDIM    256
#define TDIM    512
#define FFN     2048

typedef short bf16x8 __attribute__((ext_vector_type(8)));
typedef float f32x4  __attribute__((ext_vector_type(4)));

static __device__ __forceinline__ float bf2f(unsigned short u) {
    unsigned int i = ((unsigned int)u) << 16;
    float f; __builtin_memcpy(&f, &i, 4); return f;
}
static __device__ __forceinline__ unsigned short f2bf(float f) {
    unsigned int i; __builtin_memcpy(&i, &f, 4);
    unsigned int r = i + 0x7FFFu + ((i >> 16) & 1u);
    return (unsigned short)(r >> 16);
}

// ---------------- fold: W[K,512] x a[8,64] -> Wf[K,8] -------------------
__global__ void k_fold(const float* __restrict__ W1s, const float* __restrict__ al1,
                       const float* __restrict__ W1d, const float* __restrict__ ar1,
                       const float* __restrict__ W2,  const float* __restrict__ al2,
                       const float* __restrict__ ar2,
                       float* __restrict__ Wl1, float* __restrict__ Wr1,
                       float* __restrict__ Wl2, float* __restrict__ Wr2)
{
    int t = blockIdx.x * 256 + threadIdx.x;
    const float* W; const float* a; float* o; int rel;
    if      (t < 2048)  { W = W1s; a = al1; o = Wl1; rel = t; }
    else if (t < 6144)  { W = W1d; a = ar1; o = Wr1; rel = t - 2048; }
    else if (t < 10240) { W = W2;  a = al2; o = Wl2; rel = t - 6144; }
    else if (t < 14336) { W = W2;  a = ar2; o = Wr2; rel = t - 10240; }
    else return;
    int k = rel >> 3, h = rel & 7;
    float s = 0.f;
    for (int d = 0; d < 64; ++d) s += W[k * 512 + h * 64 + d] * a[h * 64 + d];
    o[rel] = s;
}

// ---------------- transpose f32[R,C] -> bf16[C,R] -----------------------
__global__ void k_transpose(const float* __restrict__ in, unsigned short* __restrict__ out,
                            int R, int C)
{
    __shared__ float tile[32][33];
    int c0 = blockIdx.x * 32, r0 = blockIdx.y * 32;
    int tx = threadIdx.x, ty = threadIdx.y;
#pragma unroll
    for (int i = 0; i < 4; ++i)
        tile[ty + i * 8][tx] = in[(long)(r0 + ty + i * 8) * C + c0 + tx];
    __syncthreads();
#pragma unroll
    for (int i = 0; i < 4; ++i)
        out[(long)(c0 + ty + i * 8) * R + r0 + tx] = f2bf(tile[tx][ty + i * 8]);
}

// ------- fused convert+pad+attproj for sent (K=256, el1) ----------------
// one wave per row: lane owns k = 4*lane..4*lane+3
__global__ __launch_bounds__(256)
void k_conv_sent(const float* __restrict__ X, unsigned short* __restrict__ Xb,
                 const float* __restrict__ Wl, float* __restrict__ el)
{
    __shared__ float wt[8][256];            // [head][k], 8 KB
    int tid = threadIdx.x;
    for (int i = tid; i < 2048; i += 256)
        wt[i >> 8][i & 255] = Wl[(i & 255) * 8 + (i >> 8)];
    __syncthreads();

    int row  = blockIdx.x * 4 + (tid >> 6);
    int lane = tid & 63;
    if (row >= NSENT) {
        if (row < NSENT_P) {
            uint2 z = make_uint2(0u, 0u);
            *(uint2*)(Xb + (long)row * SDIM + lane * 4) = z;
        }
        return;
    }
    float4 x = *(const float4*)(X + (long)row * SDIM + lane * 4);
    uint2 o;
    o.x = ((unsigned int)f2bf(x.x)) | (((unsigned int)f2bf(x.y)) << 16);
    o.y = ((unsigned int)f2bf(x.z)) | (((unsigned int)f2bf(x.w)) << 16);
    *(uint2*)(Xb + (long)row * SDIM + lane * 4) = o;

    float p[8];
#pragma unroll
    for (int h = 0; h < 8; ++h) {
        float4 w = *(const float4*)&wt[h][lane * 4];
        p[h] = x.x * w.x + x.y * w.y + x.z * w.z + x.w * w.w;
    }
#pragma unroll
    for (int s = 1; s < 64; s <<= 1)
#pragma unroll
        for (int h = 0; h < 8; ++h) p[h] += __shfl_xor(p[h], s);
    if (lane == 0) {
#pragma unroll
        for (int h = 0; h < 8; ++h) el[row * 8 + h] = p[h];
    }
}

// ------- fused convert+pad+attproj for sect (K=512, er1/el2/er2) --------
// one wave per row: lane owns k = 8*lane..8*lane+7
__global__ __launch_bounds__(256)
void k_conv_sect(const float* __restrict__ X, unsigned short* __restrict__ Xb,
                 const float* __restrict__ Wr1, const float* __restrict__ Wl2,
                 const float* __restrict__ Wr2,
                 float* __restrict__ er1, float* __restrict__ el2, float* __restrict__ er2)
{
    __shared__ float wt[3][8][512];         // 48 KB
    int tid = threadIdx.x;
    for (int i = tid; i < 4096; i += 256) {
        int k = i & 511, h = i >> 9;
        wt[0][h][k] = Wr1[k * 8 + h];
        wt[1][h][k] = Wl2[k * 8 + h];
        wt[2][h][k] = Wr2[k * 8 + h];
    }
    __syncthreads();

    int row  = blockIdx.x * 4 + (tid >> 6);
    int lane = tid & 63;
    if (row >= NSECT) {
        if (row < NSECT_P) {
            uint4 z = make_uint4(0u, 0u, 0u, 0u);
            *(uint4*)(Xb + (long)row * TDIM + lane * 8) = z;
        }
        return;
    }
    float4 x0 = *(const float4*)(X + (long)row * TDIM + lane * 8);
    float4 x1 = *(const float4*)(X + (long)row * TDIM + lane * 8 + 4);
    uint4 o;
    o.x = ((unsigned int)f2bf(x0.x)) | (((unsigned int)f2bf(x0.y)) << 16);
    o.y = ((unsigned int)f2bf(x0.z)) | (((unsigned int)f2bf(x0.w)) << 16);
    o.z = ((unsigned int)f2bf(x1.x)) | (((unsigned int)f2bf(x1.y)) << 16);
    o.w = ((unsigned int)f2bf(x1.z)) | (((unsigned int)f2bf(x1.w)) << 16);
    *(uint4*)(Xb + (long)row * TDIM + lane * 8) = o;

    float p[24];
#pragma unroll
    for (int m = 0; m < 3; ++m)
#pragma unroll
        for (int h = 0; h < 8; ++h) {
            float4 w0 = *(const float4*)&wt[m][h][lane * 8];
            float4 w1 = *(const float4*)&wt[m][h][lane * 8 + 4];
            p[m * 8 + h] = x0.x * w0.x + x0.y * w0.y + x0.z * w0.z + x0.w * w0.w
                         + x1.x * w1.x + x1.y * w1.y + x1.z * w1.z + x1.w * w1.w;
        }
#pragma unroll
    for (int s = 1; s < 64; s <<= 1)
#pragma unroll
        for (int j = 0; j < 24; ++j) p[j] += __shfl_xor(p[j], s);
    if (lane == 0) {
#pragma unroll
        for (int h = 0; h < 8; ++h) {
            er1[row * 8 + h] = p[h];
            el2[row * 8 + h] = p[8 + h];
            er2[row * 8 + h] = p[16 + h];
        }
    }
}

// ---------------- MFMA GEMM: C[M,N] = A[M,K]bf16 @ BT[N,K]bf16 ----------
// EPI 0: store bf16  | 1: +bias, relu, store bf16 | 2: +bias, store f32 (row<Mreal)
template<int EPI>
__global__ __launch_bounds__(256)
void k_gemm(const unsigned short* __restrict__ A, const unsigned short* __restrict__ BT,
            void* __restrict__ C, const float* __restrict__ bias,
            int N, int K, int Mreal)
{
    __shared__ unsigned short a_s[128][40];
    __shared__ unsigned short b_s[128][40];
    const int tid  = threadIdx.x;
    const int lane = tid & 63;
    const int wid  = tid >> 6;
    const int wr   = (wid >> 1) * 64;
    const int wc   = (wid & 1) * 64;
    const int row0 = blockIdx.x * 128;
    const int col0 = blockIdx.y * 128;
    const int sr   = tid >> 2;
    const int sc   = (tid & 3) * 8;

    f32x4 acc[4][4] = {};

    const unsigned short* pa0 = A + (long)(row0 + sr) * K + sc;
    const unsigned short* pa1 = pa0 + (long)64 * K;
    const unsigned short* pb0 = BT + (long)(col0 + sr) * K + sc;
    const unsigned short* pb1 = pb0 + (long)64 * K;

    for (int k0 = 0; k0 < K; k0 += 32) {
        uint4 va0 = *(const uint4*)(pa0 + k0);
        uint4 va1 = *(const uint4*)(pa1 + k0);
        uint4 vb0 = *(const uint4*)(pb0 + k0);
        uint4 vb1 = *(const uint4*)(pb1 + k0);
        __syncthreads();
        *(uint4*)&a_s[sr][sc]      = va0;
        *(uint4*)&a_s[sr + 64][sc] = va1;
        *(uint4*)&b_s[sr][sc]      = vb0;
        *(uint4*)&b_s[sr + 64][sc] = vb1;
        __syncthreads();
        bf16x8 af[4], bfr[4];
#pragma unroll
        for (int m = 0; m < 4; ++m)
            af[m] = *(const bf16x8*)&a_s[wr + m * 16 + (lane & 15)][8 * (lane >> 4)];
#pragma unroll
        for (int n = 0; n < 4; ++n)
            bfr[n] = *(const bf16x8*)&b_s[wc + n * 16 + (lane & 15)][8 * (lane >> 4)];
#pragma unroll
        for (int m = 0; m < 4; ++m)
#pragma unroll
            for (int n = 0; n < 4; ++n)
                acc[m][n] = __builtin_amdgcn_mfma_f32_16x16x32_bf16(af[m], bfr[n], acc[m][n], 0, 0, 0);
    }

#pragma unroll
    for (int m = 0; m < 4; ++m) {
        int row_t = wr + m * 16 + ((lane >> 4) << 2);
#pragma unroll
        for (int n = 0; n < 4; ++n) {
            int col = col0 + wc + n * 16 + (lane & 15);
#pragma unroll
            for (int r = 0; r < 4; ++r) {
                int row = row0 + row_t + r;
                float v = acc[m][n][r];
                if (EPI >= 1) v += bias[col];
                if (EPI == 1) v = fmaxf(v, 0.f);
                if (EPI <= 1) {
                    ((unsigned short*)C)[(long)row * N + col] = f2bf(v);
                } else {
                    if (row < Mreal) ((float*)C)[(long)row * N + col] = v;
                }
            }
        }
    }
}

// ---------------- CSR build ---------------------------------------------
__global__ void k_hist(const int* __restrict__ dst, int* __restrict__ cnt, int E)
{
    int i = blockIdx.x * 256 + threadIdx.x;
    if (i < E) atomicAdd(&cnt[dst[i]], 1);
}

__global__ void k_scan(const int* __restrict__ cnt, int* __restrict__ off,
                       int* __restrict__ cur, int Nseg)
{
    __shared__ int partial[1024];
    int t = threadIdx.x;
    int chunk = (Nseg + 1023) / 1024;
    int b = t * chunk;
    int e_ = b + chunk; if (e_ > Nseg) e_ = Nseg; if (b > Nseg) b = Nseg;
    int s = 0;
    for (int i = b; i < e_; ++i) s += cnt[i];
    partial[t] = s;
    __syncthreads();
    for (int d = 1; d < 1024; d <<= 1) {
        int v = partial[t];
        int w = (t >= d) ? partial[t - d] : 0;
        __syncthreads();
        partial[t] = v + w;
        __syncthreads();
    }
    int run = (t == 0) ? 0 : partial[t - 1];
    for (int i = b; i < e_; ++i) { off[i] = run; cur[i] = run; run += cnt[i]; }
    if (t == 1023) off[Nseg] = partial[1023];
}

__global__ void k_scatter(const int* __restrict__ src, const int* __restrict__ dst,
                          int* __restrict__ cur, int* __restrict__ srcs, int E)
{
    int i = blockIdx.x * 256 + threadIdx.x;
    if (i < E) {
        int p = atomicAdd(&cur[dst[i]], 1);
        srcs[p] = src[i];
    }
}

// ---------------- GAT aggregation: one wave per dst segment -------------
__global__ __launch_bounds__(256)
void k_aggregate(const unsigned short* __restrict__ fs, const float* __restrict__ el,
                 const float* __restrict__ er, const float* __restrict__ bias,
                 const int* __restrict__ off, const int* __restrict__ srcs,
                 float* __restrict__ out, int Ndst)
{
    int n = blockIdx.x * 4 + (threadIdx.x >> 6);
    if (n >= Ndst) return;
    int lane = threadIdx.x & 63;
    int h8 = lane & 7;
    int beg = off[n], end = off[n + 1];
    float er_h = er[n * 8 + h8];

    float mx = -3.0e38f;
    for (int p = beg + (lane >> 3); p < end; p += 8) {
        int s = srcs[p];
        float e = el[s * 8 + h8] + er_h;
        e = (e >= 0.f) ? e : 0.2f * e;
        mx = fmaxf(mx, e);
    }
    mx = fmaxf(mx, __shfl_xor(mx, 8));
    mx = fmaxf(mx, __shfl_xor(mx, 16));
    mx = fmaxf(mx, __shfl_xor(mx, 32));

    float dsum = 0.f;
    for (int p = beg + (lane >> 3); p < end; p += 8) {
        int s = srcs[p];
        float e = el[s * 8 + h8] + er_h;
        e = (e >= 0.f) ? e : 0.2f * e;
        dsum += __expf(e - mx);
    }
    dsum += __shfl_xor(dsum, 8);
    dsum += __shfl_xor(dsum, 16);
    dsum += __shfl_xor(dsum, 32);

    int hc = lane >> 3;                 // head owned by this lane's 8 dims
    float mx_c   = __shfl(mx, hc);
    float dsum_c = __shfl(dsum, hc);
    float er_c   = er[n * 8 + hc];

    float a0=0,a1=0,a2=0,a3=0,a4=0,a5=0,a6=0,a7=0;
    const unsigned short* fsl = fs + lane * 8;
    for (int p = beg; p < end; ++p) {
        int s = srcs[p];
        float e = el[s * 8 + hc] + er_c;
        e = (e >= 0.f) ? e : 0.2f * e;
        float w = __expf(e - mx_c);
        uint4 v = *(const uint4*)(fsl + (long)s * 512);
        a0 += w * bf2f((unsigned short)(v.x & 0xFFFF));
        a1 += w * bf2f((unsigned short)(v.x >> 16));
        a2 += w * bf2f((unsigned short)(v.y & 0xFFFF));
        a3 += w * bf2f((unsigned short)(v.y >> 16));
        a4 += w * bf2f((unsigned short)(v.z & 0xFFFF));
        a5 += w * bf2f((unsigned short)(v.z >> 16));
        a6 += w * bf2f((unsigned short)(v.w & 0xFFFF));
        a7 += w * bf2f((unsigned short)(v.w >> 16));
    }
    float inv = 1.f / fmaxf(dsum_c, 1e-9f);
    const float* bp = bias + lane * 8;
    float o[8] = { a0*inv + bp[0], a1*inv + bp[1], a2*inv + bp[2], a3*inv + bp[3],
                   a4*inv + bp[4], a5*inv + bp[5], a6*inv + bp[6], a7*inv + bp[7] };
#pragma unroll
    for (int j = 0; j < 8; ++j) o[j] = (o[j] > 0.f) ? o[j] : (__expf(o[j]) - 1.f);
    float4 w0 = make_float4(o[0], o[1], o[2], o[3]);
    float4 w1 = make_float4(o[4], o[5], o[6], o[7]);
    *(float4*)(out + (long)n * 512 + lane * 8)     = w0;
    *(float4*)(out + (long)n * 512 + lane * 8 + 4) = w1;
}

// ---------------- fusion gate + residual -> bf16 h ----------------------
__global__ __launch_bounds__(256)
void k_fusion(const float* __restrict__ sect, const float* __restrict__ s2S,
              const float* __restrict__ S2S, const float* __restrict__ fw,
              const float* __restrict__ fb, unsigned short* __restrict__ hout)
{
    int n = blockIdx.x * 4 + (threadIdx.x >> 6);
    if (n >= NSECT_P) return;
    int lane = threadIdx.x & 63;
    unsigned short* op = hout + (long)n * TDIM + lane * 8;
    if (n >= NSECT) {
        uint4 z = make_uint4(0u, 0u, 0u, 0u);
        *(uint4*)op = z;
        return;
    }
    long base = (long)n * TDIM + lane * 8;
    float4 p0 = *(const float4*)(s2S + base);
    float4 p1 = *(const float4*)(s2S + base + 4);
    float4 q0 = *(const float4*)(S2S + base);
    float4 q1 = *(const float4*)(S2S + base + 4);
    float4 wa0 = *(const float4*)(fw + lane * 8);
    float4 wa1 = *(const float4*)(fw + lane * 8 + 4);
    float4 wb0 = *(const float4*)(fw + 512 + lane * 8);
    float4 wb1 = *(const float4*)(fw + 512 + lane * 8 + 4);
    float part = p0.x*wa0.x + p0.y*wa0.y + p0.z*wa0.z + p0.w*wa0.w
               + p1.x*wa1.x + p1.y*wa1.y + p1.z*wa1.z + p1.w*wa1.w
               + q0.x*wb0.x + q0.y*wb0.y + q0.z*wb0.z + q0.w*wb0.w
               + q1.x*wb1.x + q1.y*wb1.y + q1.z*wb1.z + q1.w*wb1.w;
#pragma unroll
    for (int s = 1; s < 64; s <<= 1) part += __shfl_xor(part, s);
    float z = 1.f / (1.f + __expf(-(part + fb[0])));
    float4 r0 = *(const float4*)(sect + base);
    float4 r1 = *(const float4*)(sect + base + 4);
    float h[8];
    h[0] = r0.x + z * p0.x + (1.f - z) * q0.x;
    h[1] = r0.y + z * p0.y + (1.f - z) * q0.y;
    h[2] = r0.z + z * p0.z + (1.f - z) * q0.z;
    h[3] = r0.w + z * p0.w + (1.f - z) * q0.w;
    h[4] = r1.x + z * p1.x + (1.f - z) * q1.x;
    h[5] = r1.y + z * p1.y + (1.f - z) * q1.y;
    h[6] = r1.z + z * p1.z + (1.f - z) * q1.z;
    h[7] = r1.w + z * p1.w + (1.f - z) * q1.w;
    uint4 o;
    o.x = ((unsigned int)f2bf(h[0])) | (((unsigned int)f2bf(h[1])) << 16);
    o.y = ((unsigned int)f2bf(h[2])) | (((unsigned int)f2bf(h[3])) << 16);
    o.z = ((unsigned int)f2bf(h[4])) | (((unsigned int)f2bf(h[5])) << 16);
    o.w = ((unsigned int)f2bf(h[6])) | (((unsigned int)f2bf(h[7])) << 16);
    *(uint4*)op = o;
}

// ------------------------------------------------------------------------
extern "C" void kernel_launch(void* const* d_in, const int* in_sizes, int n_in,
                              void* d_out, int out_size, void* d_ws, size_t ws_size,
                              hipStream_t stream)
{
    (void)in_sizes; (void)n_in; (void)out_size; (void)ws_size;
    const float* sent    = (const float*)d_in[0];
    const float* sect    = (const float*)d_in[1];
    const int*   s2S_src = (const int*)d_in[2];
    const int*   s2S_dst = (const int*)d_in[3];
    const int*   S2S_src = (const int*)d_in[4];
    const int*   S2S_dst = (const int*)d_in[5];
    const float* W1_src  = (const float*)d_in[6];
    const float* W1_dst  = (const float*)d_in[7];
    const float* al1     = (const float*)d_in[8];
    const float* ar1     = (const float*)d_in[9];
    const float* b1      = (const float*)d_in[10];
    const float* W2      = (const float*)d_in[11];
    const float* al2     = (const float*)d_in[12];
    const float* ar2     = (const float*)d_in[13];
    const float* b2      = (const float*)d_in[14];
    const float* fus_w   = (const float*)d_in[15];
    const float* fus_b   = (const float*)d_in[16];
    const float* ffn_w1  = (const float*)d_in[17];
    const float* ffn_b1  = (const float*)d_in[18];
    const float* ffn_w2  = (const float*)d_in[19];
    const float* ffn_b2  = (const float*)d_in[20];

    char* ws = (char*)d_ws;
    size_t curo = 0;
    auto alloc = [&](size_t sz) -> void* {
        void* p = ws + curo; curo += (sz + 255) & ~(size_t)255; return p;
    };

    unsigned short* sent_b = (unsigned short*)alloc((size_t)NSENT_P * SDIM * 2);
    unsigned short* sect_b = (unsigned short*)alloc((size_t)NSECT_P * TDIM * 2);
    unsigned short* w1t    = (unsigned short*)alloc((size_t)512 * 256 * 2);
    unsigned short* w2t    = (unsigned short*)alloc((size_t)512 * 512 * 2);
    unsigned short* fw1t   = (unsigned short*)alloc((size_t)2048 * 512 * 2);
    unsigned short* fw2t   = (unsigned short*)alloc((size_t)512 * 2048 * 2);
    float* Wl1 = (float*)alloc(256 * 8 * 4);
    float* Wr1 = (float*)alloc(512 * 8 * 4);
    float* Wl2 = (float*)alloc(512 * 8 * 4);
    float* Wr2 = (float*)alloc(512 * 8 * 4);
    float* el1 = (float*)alloc((size_t)NSENT * 8 * 4);
    float* er1 = (float*)alloc((size_t)NSECT * 8 * 4);
    float* el2 = (float*)alloc((size_t)NSECT * 8 * 4);
    float* er2 = (float*)alloc((size_t)NSECT * 8 * 4);
    unsigned short* fs1 = (unsigned short*)alloc((size_t)NSENT_P * 512 * 2);
    unsigned short* f2  = (unsigned short*)alloc((size_t)NSECT_P * 512 * 2);
    int* cnt1 = (int*)alloc((size_t)NSECT * 4);
    int* cnt2 = (int*)alloc((size_t)NSECT * 4);
    int* off1 = (int*)alloc((size_t)(NSECT + 1) * 4);
    int* off2 = (int*)alloc((size_t)(NSECT + 1) * 4);
    int* cur1 = (int*)alloc((size_t)NSECT * 4);
    int* cur2 = (int*)alloc((size_t)NSECT * 4);
    int* srcs1 = (int*)alloc((size_t)E_EDGES * 4);
    int* srcs2 = (int*)alloc((size_t)E_EDGES * 4);
    float* s2Sb = (float*)alloc((size_t)NSECT * 512 * 4);
    float* S2Sb = (float*)alloc((size_t)NSECT * 512 * 4);
    unsigned short* hb = (unsigned short*)alloc((size_t)NSECT_P * TDIM * 2);
    unsigned short* tb = fs1;   // alias: t[20096,2048] bf16 (82.3MB) over fs1 (102.5MB), fs1 dead by then

    // 1. folds (must precede fused converts) + weight transposes
    k_fold<<<56, 256, 0, stream>>>(W1_src, al1, W1_dst, ar1, W2, al2, ar2, Wl1, Wr1, Wl2, Wr2);
    k_transpose<<<dim3(16, 8),  dim3(32, 8), 0, stream>>>(W1_src, w1t, 256, 512);
    k_transpose<<<dim3(16, 16), dim3(32, 8), 0, stream>>>(W2,     w2t, 512, 512);
    k_transpose<<<dim3(64, 16), dim3(32, 8), 0, stream>>>(ffn_w1, fw1t, 512, 2048);
    k_transpose<<<dim3(16, 64), dim3(32, 8), 0, stream>>>(ffn_w2, fw2t, 2048, 512);

    // 2. fused convert+pad+attention-projections
    k_conv_sent<<<NSENT_P / 4, 256, 0, stream>>>(sent, sent_b, Wl1, el1);
    k_conv_sect<<<NSECT_P / 4, 256, 0, stream>>>(sect, sect_b, Wr1, Wl2, Wr2, er1, el2, er2);

    // 3. feature GEMMs
    k_gemm<0><<<dim3(NSENT_P / 128, 4), 256, 0, stream>>>(sent_b, w1t, fs1, nullptr, 512, 256, 0);
    k_gemm<0><<<dim3(NSECT_P / 128, 4), 256, 0, stream>>>(sect_b, w2t, f2,  nullptr, 512, 512, 0);

    // 4. CSR build
    hipMemsetAsync(cnt1, 0, (size_t)NSECT * 4, stream);
    hipMemsetAsync(cnt2, 0, (size_t)NSECT * 4, stream);
    k_hist<<<E_EDGES / 256, 256, 0, stream>>>(s2S_dst, cnt1, E_EDGES);
    k_hist<<<E_EDGES / 256, 256, 0, stream>>>(S2S_dst, cnt2, E_EDGES);
    k_scan<<<1, 1024, 0, stream>>>(cnt1, off1, cur1, NSECT);
    k_scan<<<1, 1024, 0, stream>>>(cnt2, off2, cur2, NSECT);
    k_scatter<<<E_EDGES / 256, 256, 0, stream>>>(s2S_src, s2S_dst, cur1, srcs1, E_EDGES);
    k_scatter<<<E_EDGES / 256, 256, 0, stream>>>(S2S_src, S2S_dst, cur2, srcs2, E_EDGES);

    // 5. aggregation (softmax-weighted messages + bias + ELU)
    k_aggregate<<<NSECT / 4, 256, 0, stream>>>(fs1, el1, er1, b1, off1, srcs1, s2Sb, NSECT);
    k_aggregate<<<NSECT / 4, 256, 0, stream>>>(f2,  el2, er2, b2, off2, srcs2, S2Sb, NSECT);

    // 6. fusion gate + residual
    k_fusion<<<NSECT_P / 4, 256, 0, stream>>>(sect, s2Sb, S2Sb, fus_w, fus_b, hb);

    // 7. FFN
    k_gemm<1><<<dim3(NSECT_P / 128, FFN / 128), 256, 0, stream>>>(hb, fw1t, tb, ffn_b1, FFN, 512, 0);
    k_gemm<2><<<dim3(NSECT_P / 128, 4), 256, 0, stream>>>(tb, fw2t, d_out, ffn_b2, 512, FFN, NSECT);
}

// Round 3
// 652.276 us; speedup vs baseline: 1.4010x; 1.1927x over previous
//
#include <hip/hip_runtime.h>

#define E_EDGES 320000
#define NSENT   100000
#define NSENT_P 100096
#define NSECT   20000
#define NSECT_P 20096
#define SDIM    256
#define TDIM    512
#define FFN     2048

typedef short bf16x8 __attribute__((ext_vector_type(8)));
typedef float f32x4  __attribute__((ext_vector_type(4)));

static __device__ __forceinline__ float bf2f(unsigned short u) {
    unsigned int i = ((unsigned int)u) << 16;
    float f; __builtin_memcpy(&f, &i, 4); return f;
}
static __device__ __forceinline__ unsigned short f2bf(float f) {
    unsigned int i; __builtin_memcpy(&i, &f, 4);
    unsigned int r = i + 0x7FFFu + ((i >> 16) & 1u);
    return (unsigned short)(r >> 16);
}

// ---------------- fold: Wr1[k,h] = sum_d W1_dst[k, h*64+d] * ar1[h,d] ---
__global__ void k_fold(const float* __restrict__ W1d, const float* __restrict__ ar1,
                       float* __restrict__ Wr1)
{
    int t = blockIdx.x * 256 + threadIdx.x;
    if (t >= 4096) return;
    int k = t >> 3, h = t & 7;
    float s = 0.f;
    for (int d = 0; d < 64; ++d) s += W1d[k * 512 + h * 64 + d] * ar1[h * 64 + d];
    Wr1[t] = s;
}

// ---------------- transpose f32[R,C] -> bf16[C,R] -----------------------
__global__ void k_transpose(const float* __restrict__ in, unsigned short* __restrict__ out,
                            int R, int C)
{
    __shared__ float tile[32][33];
    int c0 = blockIdx.x * 32, r0 = blockIdx.y * 32;
    int tx = threadIdx.x, ty = threadIdx.y;
#pragma unroll
    for (int i = 0; i < 4; ++i)
        tile[ty + i * 8][tx] = in[(long)(r0 + ty + i * 8) * C + c0 + tx];
    __syncthreads();
#pragma unroll
    for (int i = 0; i < 4; ++i)
        out[(long)(c0 + ty + i * 8) * R + r0 + tx] = f2bf(tile[tx][ty + i * 8]);
}

// ---------------- convert f32 -> bf16, zero row padding, 8 elem/thread --
template<int LOGC>
__global__ __launch_bounds__(256)
void k_convert_pad8(const float* __restrict__ X, unsigned short* __restrict__ out,
                    int Nreal, int Npad)
{
    long i8 = (((long)blockIdx.x * 256) + threadIdx.x) * 8;
    if (i8 >= ((long)Npad << LOGC)) return;
    int row = (int)(i8 >> LOGC);
    uint4 o;
    if (row < Nreal) {
        float4 v0 = *(const float4*)(X + i8);
        float4 v1 = *(const float4*)(X + i8 + 4);
        o.x = ((unsigned int)f2bf(v0.x)) | (((unsigned int)f2bf(v0.y)) << 16);
        o.y = ((unsigned int)f2bf(v0.z)) | (((unsigned int)f2bf(v0.w)) << 16);
        o.z = ((unsigned int)f2bf(v1.x)) | (((unsigned int)f2bf(v1.y)) << 16);
        o.w = ((unsigned int)f2bf(v1.z)) | (((unsigned int)f2bf(v1.w)) << 16);
    } else { o = make_uint4(0u, 0u, 0u, 0u); }
    *(uint4*)(out + i8) = o;
}

// ------- er1 projection: out[N,8] = X[N,512] @ Wf[512,8], wave per row --
// weights live in registers: lane owns Wf rows lane*8 .. lane*8+7
__global__ __launch_bounds__(256)
void k_proj8(const float* __restrict__ X, const float* __restrict__ Wf,
             float* __restrict__ out, int Nrows)
{
    int lane = threadIdx.x & 63;
    int row  = blockIdx.x * 4 + (threadIdx.x >> 6);
    f32x4 w[16];
    const f32x4* wp = (const f32x4*)(Wf + lane * 64);
#pragma unroll
    for (int i = 0; i < 16; ++i) w[i] = wp[i];
    if (row >= Nrows) return;
    float4 x0 = *(const float4*)(X + (long)row * 512 + lane * 8);
    float4 x1 = *(const float4*)(X + (long)row * 512 + lane * 8 + 4);
    float xs[8] = {x0.x, x0.y, x0.z, x0.w, x1.x, x1.y, x1.z, x1.w};
    float p[8] = {};
#pragma unroll
    for (int j = 0; j < 8; ++j) {
        f32x4 wa = w[j * 2], wb = w[j * 2 + 1];
        p[0] += xs[j] * wa[0]; p[1] += xs[j] * wa[1];
        p[2] += xs[j] * wa[2]; p[3] += xs[j] * wa[3];
        p[4] += xs[j] * wb[0]; p[5] += xs[j] * wb[1];
        p[6] += xs[j] * wb[2]; p[7] += xs[j] * wb[3];
    }
#pragma unroll
    for (int s = 1; s < 64; s <<= 1)
#pragma unroll
        for (int h = 0; h < 8; ++h) p[h] += __shfl_xor(p[h], s);
    if (lane == 0) {
        *(float4*)(out + (long)row * 8)     = make_float4(p[0], p[1], p[2], p[3]);
        *(float4*)(out + (long)row * 8 + 4) = make_float4(p[4], p[5], p[6], p[7]);
    }
}

// ---------------- MFMA GEMM: C[M,N] = A[M,K]bf16 @ BT[N,K]bf16 ----------
// EPI 0: store bf16 | 1: +bias, relu, bf16 | 2: +bias, f32 (row<Mreal)
// NATT: 0/1/2 attention head-dot reductions from the f32 accumulator:
//   eoJ[row*8 + head] = sum_d acc[row, head*64+d] * avJ[head*64+d]
template<int EPI, int NATT>
__global__ __launch_bounds__(256)
void k_gemm(const unsigned short* __restrict__ A, const unsigned short* __restrict__ BT,
            void* __restrict__ C, const float* __restrict__ bias,
            int N, int K, int Mreal,
            const float* __restrict__ av0, float* __restrict__ eo0,
            const float* __restrict__ av1, float* __restrict__ eo1)
{
    __shared__ unsigned short a_s[128][40];
    __shared__ unsigned short b_s[128][40];
    const int tid  = threadIdx.x;
    const int lane = tid & 63;
    const int wid  = tid >> 6;
    const int wr   = (wid >> 1) * 64;
    const int wc   = (wid & 1) * 64;
    const int row0 = blockIdx.x * 128;
    const int col0 = blockIdx.y * 128;
    const int sr   = tid >> 2;
    const int sc   = (tid & 3) * 8;

    f32x4 acc[4][4] = {};

    const unsigned short* pa0 = A + (long)(row0 + sr) * K + sc;
    const unsigned short* pa1 = pa0 + (long)64 * K;
    const unsigned short* pb0 = BT + (long)(col0 + sr) * K + sc;
    const unsigned short* pb1 = pb0 + (long)64 * K;

    for (int k0 = 0; k0 < K; k0 += 32) {
        uint4 va0 = *(const uint4*)(pa0 + k0);
        uint4 va1 = *(const uint4*)(pa1 + k0);
        uint4 vb0 = *(const uint4*)(pb0 + k0);
        uint4 vb1 = *(const uint4*)(pb1 + k0);
        __syncthreads();
        *(uint4*)&a_s[sr][sc]      = va0;
        *(uint4*)&a_s[sr + 64][sc] = va1;
        *(uint4*)&b_s[sr][sc]      = vb0;
        *(uint4*)&b_s[sr + 64][sc] = vb1;
        __syncthreads();
        bf16x8 af[4], bfr[4];
#pragma unroll
        for (int m = 0; m < 4; ++m)
            af[m] = *(const bf16x8*)&a_s[wr + m * 16 + (lane & 15)][8 * (lane >> 4)];
#pragma unroll
        for (int n = 0; n < 4; ++n)
            bfr[n] = *(const bf16x8*)&b_s[wc + n * 16 + (lane & 15)][8 * (lane >> 4)];
#pragma unroll
        for (int m = 0; m < 4; ++m)
#pragma unroll
            for (int n = 0; n < 4; ++n)
                acc[m][n] = __builtin_amdgcn_mfma_f32_16x16x32_bf16(af[m], bfr[n], acc[m][n], 0, 0, 0);
    }

#pragma unroll
    for (int m = 0; m < 4; ++m) {
        int row_t = wr + m * 16 + ((lane >> 4) << 2);
#pragma unroll
        for (int n = 0; n < 4; ++n) {
            int col = col0 + wc + n * 16 + (lane & 15);
#pragma unroll
            for (int r = 0; r < 4; ++r) {
                int row = row0 + row_t + r;
                float v = acc[m][n][r];
                if (EPI >= 1) v += bias[col];
                if (EPI == 1) v = fmaxf(v, 0.f);
                if (EPI <= 1) {
                    ((unsigned short*)C)[(long)row * N + col] = f2bf(v);
                } else {
                    if (row < Mreal) ((float*)C)[(long)row * N + col] = v;
                }
            }
        }
    }

    if (NATT >= 1) {
        // this wave's 64-column stripe is exactly one head
        int hw = (col0 + wc) >> 6;
        float av0r[4], av1r[4];
#pragma unroll
        for (int n = 0; n < 4; ++n) {
            int c = col0 + wc + n * 16 + (lane & 15);
            av0r[n] = av0[c];
            if (NATT == 2) av1r[n] = av1[c];
        }
        float red0[16], red1[16];
#pragma unroll
        for (int m = 0; m < 4; ++m)
#pragma unroll
            for (int r = 0; r < 4; ++r) {
                red0[m * 4 + r] = acc[m][0][r] * av0r[0] + acc[m][1][r] * av0r[1]
                                + acc[m][2][r] * av0r[2] + acc[m][3][r] * av0r[3];
                if (NATT == 2)
                    red1[m * 4 + r] = acc[m][0][r] * av1r[0] + acc[m][1][r] * av1r[1]
                                    + acc[m][2][r] * av1r[2] + acc[m][3][r] * av1r[3];
            }
#pragma unroll
        for (int s = 1; s < 16; s <<= 1)
#pragma unroll
            for (int j = 0; j < 16; ++j) {
                red0[j] += __shfl_xor(red0[j], s);
                if (NATT == 2) red1[j] += __shfl_xor(red1[j], s);
            }
        if ((lane & 15) == 0) {
#pragma unroll
            for (int m = 0; m < 4; ++m)
#pragma unroll
                for (int r = 0; r < 4; ++r) {
                    int row = row0 + wr + m * 16 + ((lane >> 4) << 2) + r;
                    eo0[row * 8 + hw] = red0[m * 4 + r];
                    if (NATT == 2) eo1[row * 8 + hw] = red1[m * 4 + r];
                }
        }
    }
}

// ---------------- CSR build ---------------------------------------------
__global__ void k_hist(const int* __restrict__ dst, int* __restrict__ cnt, int E)
{
    int i = blockIdx.x * 256 + threadIdx.x;
    if (i < E) atomicAdd(&cnt[dst[i]], 1);
}

__global__ void k_scan(const int* __restrict__ cnt, int* __restrict__ off,
                       int* __restrict__ cur, int Nseg)
{
    __shared__ int partial[1024];
    int t = threadIdx.x;
    int chunk = (Nseg + 1023) / 1024;
    int b = t * chunk;
    int e_ = b + chunk; if (e_ > Nseg) e_ = Nseg; if (b > Nseg) b = Nseg;
    int s = 0;
    for (int i = b; i < e_; ++i) s += cnt[i];
    partial[t] = s;
    __syncthreads();
    for (int d = 1; d < 1024; d <<= 1) {
        int v = partial[t];
        int w = (t >= d) ? partial[t - d] : 0;
        __syncthreads();
        partial[t] = v + w;
        __syncthreads();
    }
    int run = (t == 0) ? 0 : partial[t - 1];
    for (int i = b; i < e_; ++i) { off[i] = run; cur[i] = run; run += cnt[i]; }
    if (t == 1023) off[Nseg] = partial[1023];
}

__global__ void k_scatter(const int* __restrict__ src, const int* __restrict__ dst,
                          int* __restrict__ cur, int* __restrict__ srcs, int E)
{
    int i = blockIdx.x * 256 + threadIdx.x;
    if (i < E) {
        int p = atomicAdd(&cur[dst[i]], 1);
        srcs[p] = src[i];
    }
}

// ---------------- GAT aggregation: one wave per dst segment -------------
__global__ __launch_bounds__(256)
void k_aggregate(const unsigned short* __restrict__ fs, const float* __restrict__ el,
                 const float* __restrict__ er, const float* __restrict__ bias,
                 const int* __restrict__ off, const int* __restrict__ srcs,
                 float* __restrict__ out, int Ndst)
{
    int n = blockIdx.x * 4 + (threadIdx.x >> 6);
    if (n >= Ndst) return;
    int lane = threadIdx.x & 63;
    int h8 = lane & 7;
    int beg = off[n], end = off[n + 1];
    float er_h = er[n * 8 + h8];

    float mx = -3.0e38f;
    for (int p = beg + (lane >> 3); p < end; p += 8) {
        int s = srcs[p];
        float e = el[s * 8 + h8] + er_h;
        e = (e >= 0.f) ? e : 0.2f * e;
        mx = fmaxf(mx, e);
    }
    mx = fmaxf(mx, __shfl_xor(mx, 8));
    mx = fmaxf(mx, __shfl_xor(mx, 16));
    mx = fmaxf(mx, __shfl_xor(mx, 32));

    float dsum = 0.f;
    for (int p = beg + (lane >> 3); p < end; p += 8) {
        int s = srcs[p];
        float e = el[s * 8 + h8] + er_h;
        e = (e >= 0.f) ? e : 0.2f * e;
        dsum += __expf(e - mx);
    }
    dsum += __shfl_xor(dsum, 8);
    dsum += __shfl_xor(dsum, 16);
    dsum += __shfl_xor(dsum, 32);

    int hc = lane >> 3;                 // head owned by this lane's 8 dims
    float mx_c   = __shfl(mx, hc);
    float dsum_c = __shfl(dsum, hc);
    float er_c   = er[n * 8 + hc];

    float a0=0,a1=0,a2=0,a3=0,a4=0,a5=0,a6=0,a7=0;
    const unsigned short* fsl = fs + lane * 8;
    for (int p = beg; p < end; ++p) {
        int s = srcs[p];
        float e = el[s * 8 + hc] + er_c;
        e = (e >= 0.f) ? e : 0.2f * e;
        float w = __expf(e - mx_c);
        uint4 v = *(const uint4*)(fsl + (long)s * 512);
        a0 += w * bf2f((unsigned short)(v.x & 0xFFFF));
        a1 += w * bf2f((unsigned short)(v.x >> 16));
        a2 += w * bf2f((unsigned short)(v.y & 0xFFFF));
        a3 += w * bf2f((unsigned short)(v.y >> 16));
        a4 += w * bf2f((unsigned short)(v.z & 0xFFFF));
        a5 += w * bf2f((unsigned short)(v.z >> 16));
        a6 += w * bf2f((unsigned short)(v.w & 0xFFFF));
        a7 += w * bf2f((unsigned short)(v.w >> 16));
    }
    float inv = 1.f / fmaxf(dsum_c, 1e-9f);
    const float* bp = bias + lane * 8;
    float o[8] = { a0*inv + bp[0], a1*inv + bp[1], a2*inv + bp[2], a3*inv + bp[3],
                   a4*inv + bp[4], a5*inv + bp[5], a6*inv + bp[6], a7*inv + bp[7] };
#pragma unroll
    for (int j = 0; j < 8; ++j) o[j] = (o[j] > 0.f) ? o[j] : (__expf(o[j]) - 1.f);
    float4 w0 = make_float4(o[0], o[1], o[2], o[3]);
    float4 w1 = make_float4(o[4], o[5], o[6], o[7]);
    *(float4*)(out + (long)n * 512 + lane * 8)     = w0;
    *(float4*)(out + (long)n * 512 + lane * 8 + 4) = w1;
}

// ---------------- fusion gate + residual -> bf16 h ----------------------
__global__ __launch_bounds__(256)
void k_fusion(const float* __restrict__ sect, const float* __restrict__ s2S,
              const float* __restrict__ S2S, const float* __restrict__ fw,
              const float* __restrict__ fb, unsigned short* __restrict__ hout)
{
    int n = blockIdx.x * 4 + (threadIdx.x >> 6);
    if (n >= NSECT_P) return;
    int lane = threadIdx.x & 63;
    unsigned short* op = hout + (long)n * TDIM + lane * 8;
    if (n >= NSECT) {
        uint4 z = make_uint4(0u, 0u, 0u, 0u);
        *(uint4*)op = z;
        return;
    }
    long base = (long)n * TDIM + lane * 8;
    float4 p0 = *(const float4*)(s2S + base);
    float4 p1 = *(const float4*)(s2S + base + 4);
    float4 q0 = *(const float4*)(S2S + base);
    float4 q1 = *(const float4*)(S2S + base + 4);
    float4 wa0 = *(const float4*)(fw + lane * 8);
    float4 wa1 = *(const float4*)(fw + lane * 8 + 4);
    float4 wb0 = *(const float4*)(fw + 512 + lane * 8);
    float4 wb1 = *(const float4*)(fw + 512 + lane * 8 + 4);
    float part = p0.x*wa0.x + p0.y*wa0.y + p0.z*wa0.z + p0.w*wa0.w
               + p1.x*wa1.x + p1.y*wa1.y + p1.z*wa1.z + p1.w*wa1.w
               + q0.x*wb0.x + q0.y*wb0.y + q0.z*wb0.z + q0.w*wb0.w
               + q1.x*wb1.x + q1.y*wb1.y + q1.z*wb1.z + q1.w*wb1.w;
#pragma unroll
    for (int s = 1; s < 64; s <<= 1) part += __shfl_xor(part, s);
    float z = 1.f / (1.f + __expf(-(part + fb[0])));
    float4 r0 = *(const float4*)(sect + base);
    float4 r1 = *(const float4*)(sect + base + 4);
    float h[8];
    h[0] = r0.x + z * p0.x + (1.f - z) * q0.x;
    h[1] = r0.y + z * p0.y + (1.f - z) * q0.y;
    h[2] = r0.z + z * p0.z + (1.f - z) * q0.z;
    h[3] = r0.w + z * p0.w + (1.f - z) * q0.w;
    h[4] = r1.x + z * p1.x + (1.f - z) * q1.x;
    h[5] = r1.y + z * p1.y + (1.f - z) * q1.y;
    h[6] = r1.z + z * p1.z + (1.f - z) * q1.z;
    h[7] = r1.w + z * p1.w + (1.f - z) * q1.w;
    uint4 o;
    o.x = ((unsigned int)f2bf(h[0])) | (((unsigned int)f2bf(h[1])) << 16);
    o.y = ((unsigned int)f2bf(h[2])) | (((unsigned int)f2bf(h[3])) << 16);
    o.z = ((unsigned int)f2bf(h[4])) | (((unsigned int)f2bf(h[5])) << 16);
    o.w = ((unsigned int)f2bf(h[6])) | (((unsigned int)f2bf(h[7])) << 16);
    *(uint4*)op = o;
}

// ------------------------------------------------------------------------
extern "C" void kernel_launch(void* const* d_in, const int* in_sizes, int n_in,
                              void* d_out, int out_size, void* d_ws, size_t ws_size,
                              hipStream_t stream)
{
    (void)in_sizes; (void)n_in; (void)out_size; (void)ws_size;
    const float* sent    = (const float*)d_in[0];
    const float* sect    = (const float*)d_in[1];
    const int*   s2S_src = (const int*)d_in[2];
    const int*   s2S_dst = (const int*)d_in[3];
    const int*   S2S_src = (const int*)d_in[4];
    const int*   S2S_dst = (const int*)d_in[5];
    const float* W1_src  = (const float*)d_in[6];
    const float* W1_dst  = (const float*)d_in[7];
    const float* al1     = (const float*)d_in[8];
    const float* ar1     = (const float*)d_in[9];
    const float* b1      = (const float*)d_in[10];
    const float* W2      = (const float*)d_in[11];
    const float* al2     = (const float*)d_in[12];
    const float* ar2     = (const float*)d_in[13];
    const float* b2      = (const float*)d_in[14];
    const float* fus_w   = (const float*)d_in[15];
    const float* fus_b   = (const float*)d_in[16];
    const float* ffn_w1  = (const float*)d_in[17];
    const float* ffn_b1  = (const float*)d_in[18];
    const float* ffn_w2  = (const float*)d_in[19];
    const float* ffn_b2  = (const float*)d_in[20];

    char* ws = (char*)d_ws;
    size_t curo = 0;
    auto alloc = [&](size_t sz) -> void* {
        void* p = ws + curo; curo += (sz + 255) & ~(size_t)255; return p;
    };

    unsigned short* sent_b = (unsigned short*)alloc((size_t)NSENT_P * SDIM * 2);
    unsigned short* sect_b = (unsigned short*)alloc((size_t)NSECT_P * TDIM * 2);
    unsigned short* w1t    = (unsigned short*)alloc((size_t)512 * 256 * 2);
    unsigned short* w2t    = (unsigned short*)alloc((size_t)512 * 512 * 2);
    unsigned short* fw1t   = (unsigned short*)alloc((size_t)2048 * 512 * 2);
    unsigned short* fw2t   = (unsigned short*)alloc((size_t)512 * 2048 * 2);
    float* Wr1 = (float*)alloc(512 * 8 * 4);
    float* el1 = (float*)alloc((size_t)NSENT_P * 8 * 4);
    float* er1 = (float*)alloc((size_t)NSECT_P * 8 * 4);
    float* el2 = (float*)alloc((size_t)NSECT_P * 8 * 4);
    float* er2 = (float*)alloc((size_t)NSECT_P * 8 * 4);
    unsigned short* fs1 = (unsigned short*)alloc((size_t)NSENT_P * 512 * 2);
    unsigned short* f2  = (unsigned short*)alloc((size_t)NSECT_P * 512 * 2);
    int* cnt1 = (int*)alloc((size_t)NSECT * 4);
    int* cnt2 = (int*)alloc((size_t)NSECT * 4);
    int* off1 = (int*)alloc((size_t)(NSECT + 1) * 4);
    int* off2 = (int*)alloc((size_t)(NSECT + 1) * 4);
    int* cur1 = (int*)alloc((size_t)NSECT * 4);
    int* cur2 = (int*)alloc((size_t)NSECT * 4);
    int* srcs1 = (int*)alloc((size_t)E_EDGES * 4);
    int* srcs2 = (int*)alloc((size_t)E_EDGES * 4);
    float* s2Sb = (float*)alloc((size_t)NSECT * 512 * 4);
    float* S2Sb = (float*)alloc((size_t)NSECT * 512 * 4);
    unsigned short* hb = (unsigned short*)alloc((size_t)NSECT_P * TDIM * 2);
    unsigned short* tb = fs1;   // alias: t[20096,2048] bf16 over fs1, fs1 dead by then

    // 1. fold (er1 weights) + weight transposes
    k_fold<<<16, 256, 0, stream>>>(W1_dst, ar1, Wr1);
    k_transpose<<<dim3(16, 8),  dim3(32, 8), 0, stream>>>(W1_src, w1t, 256, 512);
    k_transpose<<<dim3(16, 16), dim3(32, 8), 0, stream>>>(W2,     w2t, 512, 512);
    k_transpose<<<dim3(64, 16), dim3(32, 8), 0, stream>>>(ffn_w1, fw1t, 512, 2048);
    k_transpose<<<dim3(16, 64), dim3(32, 8), 0, stream>>>(ffn_w2, fw2t, 2048, 512);

    // 2. pure streaming converts + er1 projection
    k_convert_pad8<8><<<(int)(((long)NSENT_P * SDIM / 8 + 255) / 256), 256, 0, stream>>>(sent, sent_b, NSENT, NSENT_P);
    k_convert_pad8<9><<<(int)(((long)NSECT_P * TDIM / 8 + 255) / 256), 256, 0, stream>>>(sect, sect_b, NSECT, NSECT_P);
    k_proj8<<<NSECT / 4, 256, 0, stream>>>(sect, Wr1, er1, NSECT);

    // 3. feature GEMMs with fused attention-logit reductions
    k_gemm<0, 1><<<dim3(NSENT_P / 128, 4), 256, 0, stream>>>(sent_b, w1t, fs1, nullptr, 512, 256, 0, al1, el1, nullptr, nullptr);
    k_gemm<0, 2><<<dim3(NSECT_P / 128, 4), 256, 0, stream>>>(sect_b, w2t, f2,  nullptr, 512, 512, 0, al2, el2, ar2, er2);

    // 4. CSR build
    hipMemsetAsync(cnt1, 0, (size_t)NSECT * 4, stream);
    hipMemsetAsync(cnt2, 0, (size_t)NSECT * 4, stream);
    k_hist<<<E_EDGES / 256, 256, 0, stream>>>(s2S_dst, cnt1, E_EDGES);
    k_hist<<<E_EDGES / 256, 256, 0, stream>>>(S2S_dst, cnt2, E_EDGES);
    k_scan<<<1, 1024, 0, stream>>>(cnt1, off1, cur1, NSECT);
    k_scan<<<1, 1024, 0, stream>>>(cnt2, off2, cur2, NSECT);
    k_scatter<<<E_EDGES / 256, 256, 0, stream>>>(s2S_src, s2S_dst, cur1, srcs1, E_EDGES);
    k_scatter<<<E_EDGES / 256, 256, 0, stream>>>(S2S_src, S2S_dst, cur2, srcs2, E_EDGES);

    // 5. aggregation (softmax-weighted messages + bias + ELU)
    k_aggregate<<<NSECT / 4, 256, 0, stream>>>(fs1, el1, er1, b1, off1, srcs1, s2Sb, NSECT);
    k_aggregate<<<NSECT / 4, 256, 0, stream>>>(f2,  el2, er2, b2, off2, srcs2, S2Sb, NSECT);

    // 6. fusion gate + residual
    k_fusion<<<NSECT_P / 4, 256, 0, stream>>>(sect, s2Sb, S2Sb, fus_w, fus_b, hb);

    // 7. FFN
    k_gemm<1, 0><<<dim3(NSECT_P / 128, FFN / 128), 256, 0, stream>>>(hb, fw1t, tb, ffn_b1, FFN, 512, 0, nullptr, nullptr, nullptr, nullptr);
    k_gemm<2, 0><<<dim3(NSECT_P / 128, 4), 256, 0, stream>>>(tb, fw2t, d_out, ffn_b2, 512, FFN, NSECT, nullptr, nullptr, nullptr, nullptr);
}

// Round 4
// 646.103 us; speedup vs baseline: 1.4144x; 1.0096x over previous
//
#include <hip/hip_runtime.h>

#define E_EDGES 320000
#define NSENT   100000
#define NSENT_P 100096
#define NSECT   20000
#define NSECT_P 20096
#define SDIM    256
#define TDIM    512
#define FFN     2048

typedef short bf16x8 __attribute__((ext_vector_type(8)));
typedef float f32x4  __attribute__((ext_vector_type(4)));

static __device__ __forceinline__ float bf2f(unsigned short u) {
    unsigned int i = ((unsigned int)u) << 16;
    float f; __builtin_memcpy(&f, &i, 4); return f;
}
static __device__ __forceinline__ unsigned short f2bf(float f) {
    unsigned int i; __builtin_memcpy(&i, &f, 4);
    unsigned int r = i + 0x7FFFu + ((i >> 16) & 1u);
    return (unsigned short)(r >> 16);
}

// ---------------- fold: Wr1[k,h] = sum_d W1_dst[k, h*64+d] * ar1[h,d] ---
__global__ void k_fold(const float* __restrict__ W1d, const float* __restrict__ ar1,
                       float* __restrict__ Wr1)
{
    int t = blockIdx.x * 256 + threadIdx.x;
    if (t >= 4096) return;
    int k = t >> 3, h = t & 7;
    float s = 0.f;
    for (int d = 0; d < 64; ++d) s += W1d[k * 512 + h * 64 + d] * ar1[h * 64 + d];
    Wr1[t] = s;
}

// ---------------- transpose f32[R,C] -> bf16[C,R] -----------------------
__global__ void k_transpose(const float* __restrict__ in, unsigned short* __restrict__ out,
                            int R, int C)
{
    __shared__ float tile[32][33];
    int c0 = blockIdx.x * 32, r0 = blockIdx.y * 32;
    int tx = threadIdx.x, ty = threadIdx.y;
#pragma unroll
    for (int i = 0; i < 4; ++i)
        tile[ty + i * 8][tx] = in[(long)(r0 + ty + i * 8) * C + c0 + tx];
    __syncthreads();
#pragma unroll
    for (int i = 0; i < 4; ++i)
        out[(long)(c0 + ty + i * 8) * R + r0 + tx] = f2bf(tile[tx][ty + i * 8]);
}

// ---------------- convert f32 -> bf16, zero row padding, 8 elem/thread --
template<int LOGC>
__global__ __launch_bounds__(256)
void k_convert_pad8(const float* __restrict__ X, unsigned short* __restrict__ out,
                    int Nreal, int Npad)
{
    long i8 = (((long)blockIdx.x * 256) + threadIdx.x) * 8;
    if (i8 >= ((long)Npad << LOGC)) return;
    int row = (int)(i8 >> LOGC);
    uint4 o;
    if (row < Nreal) {
        float4 v0 = *(const float4*)(X + i8);
        float4 v1 = *(const float4*)(X + i8 + 4);
        o.x = ((unsigned int)f2bf(v0.x)) | (((unsigned int)f2bf(v0.y)) << 16);
        o.y = ((unsigned int)f2bf(v0.z)) | (((unsigned int)f2bf(v0.w)) << 16);
        o.z = ((unsigned int)f2bf(v1.x)) | (((unsigned int)f2bf(v1.y)) << 16);
        o.w = ((unsigned int)f2bf(v1.z)) | (((unsigned int)f2bf(v1.w)) << 16);
    } else { o = make_uint4(0u, 0u, 0u, 0u); }
    *(uint4*)(out + i8) = o;
}

// ------- er1 projection: out[N,8] = X[N,512] @ Wf[512,8], wave per row --
__global__ __launch_bounds__(256)
void k_proj8(const float* __restrict__ X, const float* __restrict__ Wf,
             float* __restrict__ out, int Nrows)
{
    int lane = threadIdx.x & 63;
    int row  = blockIdx.x * 4 + (threadIdx.x >> 6);
    f32x4 w[16];
    const f32x4* wp = (const f32x4*)(Wf + lane * 64);
#pragma unroll
    for (int i = 0; i < 16; ++i) w[i] = wp[i];
    if (row >= Nrows) return;
    float4 x0 = *(const float4*)(X + (long)row * 512 + lane * 8);
    float4 x1 = *(const float4*)(X + (long)row * 512 + lane * 8 + 4);
    float xs[8] = {x0.x, x0.y, x0.z, x0.w, x1.x, x1.y, x1.z, x1.w};
    float p[8] = {};
#pragma unroll
    for (int j = 0; j < 8; ++j) {
        f32x4 wa = w[j * 2], wb = w[j * 2 + 1];
        p[0] += xs[j] * wa[0]; p[1] += xs[j] * wa[1];
        p[2] += xs[j] * wa[2]; p[3] += xs[j] * wa[3];
        p[4] += xs[j] * wb[0]; p[5] += xs[j] * wb[1];
        p[6] += xs[j] * wb[2]; p[7] += xs[j] * wb[3];
    }
#pragma unroll
    for (int s = 1; s < 64; s <<= 1)
#pragma unroll
        for (int h = 0; h < 8; ++h) p[h] += __shfl_xor(p[h], s);
    if (lane == 0) {
        *(float4*)(out + (long)row * 8)     = make_float4(p[0], p[1], p[2], p[3]);
        *(float4*)(out + (long)row * 8 + 4) = make_float4(p[4], p[5], p[6], p[7]);
    }
}

// ---------------- MFMA GEMM: C[M,N] = A[M,K]bf16 @ BT[N,K]bf16 ----------
// Tile: (32*MT) x 128, 4 waves as 2x2, per-wave acc[MT][4] of 16x16.
// 1-D grid, N-fastest tile order, bijective XCD swizzle (m204).
// EPI 0: store bf16 | 1: +bias, relu, bf16 | 2: +bias, f32 (row<Mreal)
// NATT: 0/1/2 head-dot reductions from the f32 accumulator.
template<int EPI, int NATT, int MT>
__global__ __launch_bounds__(256)
void k_gemm(const unsigned short* __restrict__ A, const unsigned short* __restrict__ BT,
            void* __restrict__ C, const float* __restrict__ bias,
            int N, int K, int Mreal, int ntx,
            const float* __restrict__ av0, float* __restrict__ eo0,
            const float* __restrict__ av1, float* __restrict__ eo1)
{
    __shared__ unsigned short a_s[MT * 32][40];
    __shared__ unsigned short b_s[128][40];
    const int tid  = threadIdx.x;
    const int lane = tid & 63;
    const int wid  = tid >> 6;
    const int wr   = (wid >> 1) * (16 * MT);
    const int wc   = (wid & 1) * 64;

    // bijective XCD-contiguous remap: physical bid -> logical tile wgid
    const int nwg = gridDim.x;
    const int bid = blockIdx.x;
    const int q = nwg >> 3, r = nwg & 7;
    const int xcd = bid & 7;
    const int wgid = (xcd < r ? xcd * (q + 1) : r * (q + 1) + (xcd - r) * q) + (bid >> 3);
    const int row0 = (wgid / ntx) * (32 * MT);
    const int col0 = (wgid % ntx) * 128;

    const int sr   = tid >> 2;
    const int sc   = (tid & 3) * 8;

    f32x4 acc[MT][4] = {};

    const unsigned short* pa0 = A + (long)(row0 + sr) * K + sc;
    const unsigned short* pa1 = pa0 + (long)64 * K;   // used only when MT==4
    const unsigned short* pb0 = BT + (long)(col0 + sr) * K + sc;
    const unsigned short* pb1 = pb0 + (long)64 * K;

    for (int k0 = 0; k0 < K; k0 += 32) {
        uint4 va0 = *(const uint4*)(pa0 + k0);
        uint4 va1;
        if (MT == 4) va1 = *(const uint4*)(pa1 + k0);
        uint4 vb0 = *(const uint4*)(pb0 + k0);
        uint4 vb1 = *(const uint4*)(pb1 + k0);
        __syncthreads();
        *(uint4*)&a_s[sr][sc] = va0;
        if (MT == 4) *(uint4*)&a_s[sr + 64][sc] = va1;
        *(uint4*)&b_s[sr][sc]      = vb0;
        *(uint4*)&b_s[sr + 64][sc] = vb1;
        __syncthreads();
        bf16x8 af[MT], bfr[4];
#pragma unroll
        for (int m = 0; m < MT; ++m)
            af[m] = *(const bf16x8*)&a_s[wr + m * 16 + (lane & 15)][8 * (lane >> 4)];
#pragma unroll
        for (int n = 0; n < 4; ++n)
            bfr[n] = *(const bf16x8*)&b_s[wc + n * 16 + (lane & 15)][8 * (lane >> 4)];
#pragma unroll
        for (int m = 0; m < MT; ++m)
#pragma unroll
            for (int n = 0; n < 4; ++n)
                acc[m][n] = __builtin_amdgcn_mfma_f32_16x16x32_bf16(af[m], bfr[n], acc[m][n], 0, 0, 0);
    }

#pragma unroll
    for (int m = 0; m < MT; ++m) {
        int row_t = wr + m * 16 + ((lane >> 4) << 2);
#pragma unroll
        for (int n = 0; n < 4; ++n) {
            int col = col0 + wc + n * 16 + (lane & 15);
#pragma unroll
            for (int r2 = 0; r2 < 4; ++r2) {
                int row = row0 + row_t + r2;
                float v = acc[m][n][r2];
                if (EPI >= 1) v += bias[col];
                if (EPI == 1) v = fmaxf(v, 0.f);
                if (EPI <= 1) {
                    ((unsigned short*)C)[(long)row * N + col] = f2bf(v);
                } else {
                    if (row < Mreal) ((float*)C)[(long)row * N + col] = v;
                }
            }
        }
    }

    if (NATT >= 1) {
        // this wave's 64-column stripe is exactly one head
        int hw = (col0 + wc) >> 6;
        float av0r[4], av1r[4];
#pragma unroll
        for (int n = 0; n < 4; ++n) {
            int c = col0 + wc + n * 16 + (lane & 15);
            av0r[n] = av0[c];
            if (NATT == 2) av1r[n] = av1[c];
        }
        float red0[MT * 4], red1[MT * 4];
#pragma unroll
        for (int m = 0; m < MT; ++m)
#pragma unroll
            for (int r2 = 0; r2 < 4; ++r2) {
                red0[m * 4 + r2] = acc[m][0][r2] * av0r[0] + acc[m][1][r2] * av0r[1]
                                 + acc[m][2][r2] * av0r[2] + acc[m][3][r2] * av0r[3];
                if (NATT == 2)
                    red1[m * 4 + r2] = acc[m][0][r2] * av1r[0] + acc[m][1][r2] * av1r[1]
                                     + acc[m][2][r2] * av1r[2] + acc[m][3][r2] * av1r[3];
            }
#pragma unroll
        for (int s = 1; s < 16; s <<= 1)
#pragma unroll
            for (int j = 0; j < MT * 4; ++j) {
                red0[j] += __shfl_xor(red0[j], s);
                if (NATT == 2) red1[j] += __shfl_xor(red1[j], s);
            }
        if ((lane & 15) == 0) {
#pragma unroll
            for (int m = 0; m < MT; ++m)
#pragma unroll
                for (int r2 = 0; r2 < 4; ++r2) {
                    int row = row0 + wr + m * 16 + ((lane >> 4) << 2) + r2;
                    eo0[row * 8 + hw] = red0[m * 4 + r2];
                    if (NATT == 2) eo1[row * 8 + hw] = red1[m * 4 + r2];
                }
        }
    }
}

// ---------------- CSR build ---------------------------------------------
__global__ void k_hist(const int* __restrict__ dst, int* __restrict__ cnt, int E)
{
    int i = blockIdx.x * 256 + threadIdx.x;
    if (i < E) atomicAdd(&cnt[dst[i]], 1);
}

__global__ void k_scan(const int* __restrict__ cnt, int* __restrict__ off,
                       int* __restrict__ cur, int Nseg)
{
    __shared__ int partial[1024];
    int t = threadIdx.x;
    int chunk = (Nseg + 1023) / 1024;
    int b = t * chunk;
    int e_ = b + chunk; if (e_ > Nseg) e_ = Nseg; if (b > Nseg) b = Nseg;
    int s = 0;
    for (int i = b; i < e_; ++i) s += cnt[i];
    partial[t] = s;
    __syncthreads();
    for (int d = 1; d < 1024; d <<= 1) {
        int v = partial[t];
        int w = (t >= d) ? partial[t - d] : 0;
        __syncthreads();
        partial[t] = v + w;
        __syncthreads();
    }
    int run = (t == 0) ? 0 : partial[t - 1];
    for (int i = b; i < e_; ++i) { off[i] = run; cur[i] = run; run += cnt[i]; }
    if (t == 1023) off[Nseg] = partial[1023];
}

__global__ void k_scatter(const int* __restrict__ src, const int* __restrict__ dst,
                          int* __restrict__ cur, int* __restrict__ srcs, int E)
{
    int i = blockIdx.x * 256 + threadIdx.x;
    if (i < E) {
        int p = atomicAdd(&cur[dst[i]], 1);
        srcs[p] = src[i];
    }
}

// ---------------- GAT aggregation: one wave per dst segment -------------
__global__ __launch_bounds__(256)
void k_aggregate(const unsigned short* __restrict__ fs, const float* __restrict__ el,
                 const float* __restrict__ er, const float* __restrict__ bias,
                 const int* __restrict__ off, const int* __restrict__ srcs,
                 float* __restrict__ out, int Ndst)
{
    int n = blockIdx.x * 4 + (threadIdx.x >> 6);
    if (n >= Ndst) return;
    int lane = threadIdx.x & 63;
    int h8 = lane & 7;
    int beg = off[n], end = off[n + 1];
    float er_h = er[n * 8 + h8];

    float mx = -3.0e38f;
    for (int p = beg + (lane >> 3); p < end; p += 8) {
        int s = srcs[p];
        float e = el[s * 8 + h8] + er_h;
        e = (e >= 0.f) ? e : 0.2f * e;
        mx = fmaxf(mx, e);
    }
    mx = fmaxf(mx, __shfl_xor(mx, 8));
    mx = fmaxf(mx, __shfl_xor(mx, 16));
    mx = fmaxf(mx, __shfl_xor(mx, 32));

    float dsum = 0.f;
    for (int p = beg + (lane >> 3); p < end; p += 8) {
        int s = srcs[p];
        float e = el[s * 8 + h8] + er_h;
        e = (e >= 0.f) ? e : 0.2f * e;
        dsum += __expf(e - mx);
    }
    dsum += __shfl_xor(dsum, 8);
    dsum += __shfl_xor(dsum, 16);
    dsum += __shfl_xor(dsum, 32);

    int hc = lane >> 3;                 // head owned by this lane's 8 dims
    float mx_c   = __shfl(mx, hc);
    float dsum_c = __shfl(dsum, hc);
    float er_c   = er[n * 8 + hc];

    float a0=0,a1=0,a2=0,a3=0,a4=0,a5=0,a6=0,a7=0;
    const unsigned short* fsl = fs + lane * 8;
    for (int p = beg; p < end; ++p) {
        int s = srcs[p];
        float e = el[s * 8 + hc] + er_c;
        e = (e >= 0.f) ? e : 0.2f * e;
        float w = __expf(e - mx_c);
        uint4 v = *(const uint4*)(fsl + (long)s * 512);
        a0 += w * bf2f((unsigned short)(v.x & 0xFFFF));
        a1 += w * bf2f((unsigned short)(v.x >> 16));
        a2 += w * bf2f((unsigned short)(v.y & 0xFFFF));
        a3 += w * bf2f((unsigned short)(v.y >> 16));
        a4 += w * bf2f((unsigned short)(v.z & 0xFFFF));
        a5 += w * bf2f((unsigned short)(v.z >> 16));
        a6 += w * bf2f((unsigned short)(v.w & 0xFFFF));
        a7 += w * bf2f((unsigned short)(v.w >> 16));
    }
    float inv = 1.f / fmaxf(dsum_c, 1e-9f);
    const float* bp = bias + lane * 8;
    float o[8] = { a0*inv + bp[0], a1*inv + bp[1], a2*inv + bp[2], a3*inv + bp[3],
                   a4*inv + bp[4], a5*inv + bp[5], a6*inv + bp[6], a7*inv + bp[7] };
#pragma unroll
    for (int j = 0; j < 8; ++j) o[j] = (o[j] > 0.f) ? o[j] : (__expf(o[j]) - 1.f);
    float4 w0 = make_float4(o[0], o[1], o[2], o[3]);
    float4 w1 = make_float4(o[4], o[5], o[6], o[7]);
    *(float4*)(out + (long)n * 512 + lane * 8)     = w0;
    *(float4*)(out + (long)n * 512 + lane * 8 + 4) = w1;
}

// ---------------- fusion gate + residual -> bf16 h ----------------------
__global__ __launch_bounds__(256)
void k_fusion(const float* __restrict__ sect, const float* __restrict__ s2S,
              const float* __restrict__ S2S, const float* __restrict__ fw,
              const float* __restrict__ fb, unsigned short* __restrict__ hout)
{
    int n = blockIdx.x * 4 + (threadIdx.x >> 6);
    if (n >= NSECT_P) return;
    int lane = threadIdx.x & 63;
    unsigned short* op = hout + (long)n * TDIM + lane * 8;
    if (n >= NSECT) {
        uint4 z = make_uint4(0u, 0u, 0u, 0u);
        *(uint4*)op = z;
        return;
    }
    long base = (long)n * TDIM + lane * 8;
    float4 p0 = *(const float4*)(s2S + base);
    float4 p1 = *(const float4*)(s2S + base + 4);
    float4 q0 = *(const float4*)(S2S + base);
    float4 q1 = *(const float4*)(S2S + base + 4);
    float4 wa0 = *(const float4*)(fw + lane * 8);
    float4 wa1 = *(const float4*)(fw + lane * 8 + 4);
    float4 wb0 = *(const float4*)(fw + 512 + lane * 8);
    float4 wb1 = *(const float4*)(fw + 512 + lane * 8 + 4);
    float part = p0.x*wa0.x + p0.y*wa0.y + p0.z*wa0.z + p0.w*wa0.w
               + p1.x*wa1.x + p1.y*wa1.y + p1.z*wa1.z + p1.w*wa1.w
               + q0.x*wb0.x + q0.y*wb0.y + q0.z*wb0.z + q0.w*wb0.w
               + q1.x*wb1.x + q1.y*wb1.y + q1.z*wb1.z + q1.w*wb1.w;
#pragma unroll
    for (int s = 1; s < 64; s <<= 1) part += __shfl_xor(part, s);
    float z = 1.f / (1.f + __expf(-(part + fb[0])));
    float4 r0 = *(const float4*)(sect + base);
    float4 r1 = *(const float4*)(sect + base + 4);
    float h[8];
    h[0] = r0.x + z * p0.x + (1.f - z) * q0.x;
    h[1] = r0.y + z * p0.y + (1.f - z) * q0.y;
    h[2] = r0.z + z * p0.z + (1.f - z) * q0.z;
    h[3] = r0.w + z * p0.w + (1.f - z) * q0.w;
    h[4] = r1.x + z * p1.x + (1.f - z) * q1.x;
    h[5] = r1.y + z * p1.y + (1.f - z) * q1.y;
    h[6] = r1.z + z * p1.z + (1.f - z) * q1.z;
    h[7] = r1.w + z * p1.w + (1.f - z) * q1.w;
    uint4 o;
    o.x = ((unsigned int)f2bf(h[0])) | (((unsigned int)f2bf(h[1])) << 16);
    o.y = ((unsigned int)f2bf(h[2])) | (((unsigned int)f2bf(h[3])) << 16);
    o.z = ((unsigned int)f2bf(h[4])) | (((unsigned int)f2bf(h[5])) << 16);
    o.w = ((unsigned int)f2bf(h[6])) | (((unsigned int)f2bf(h[7])) << 16);
    *(uint4*)op = o;
}

// ------------------------------------------------------------------------
extern "C" void kernel_launch(void* const* d_in, const int* in_sizes, int n_in,
                              void* d_out, int out_size, void* d_ws, size_t ws_size,
                              hipStream_t stream)
{
    (void)in_sizes; (void)n_in; (void)out_size; (void)ws_size;
    const float* sent    = (const float*)d_in[0];
    const float* sect    = (const float*)d_in[1];
    const int*   s2S_src = (const int*)d_in[2];
    const int*   s2S_dst = (const int*)d_in[3];
    const int*   S2S_src = (const int*)d_in[4];
    const int*   S2S_dst = (const int*)d_in[5];
    const float* W1_src  = (const float*)d_in[6];
    const float* W1_dst  = (const float*)d_in[7];
    const float* al1     = (const float*)d_in[8];
    const float* ar1     = (const float*)d_in[9];
    const float* b1      = (const float*)d_in[10];
    const float* W2      = (const float*)d_in[11];
    const float* al2     = (const float*)d_in[12];
    const float* ar2     = (const float*)d_in[13];
    const float* b2      = (const float*)d_in[14];
    const float* fus_w   = (const float*)d_in[15];
    const float* fus_b   = (const float*)d_in[16];
    const float* ffn_w1  = (const float*)d_in[17];
    const float* ffn_b1  = (const float*)d_in[18];
    const float* ffn_w2  = (const float*)d_in[19];
    const float* ffn_b2  = (const float*)d_in[20];

    char* ws = (char*)d_ws;
    size_t curo = 0;
    auto alloc = [&](size_t sz) -> void* {
        void* p = ws + curo; curo += (sz + 255) & ~(size_t)255; return p;
    };

    unsigned short* sent_b = (unsigned short*)alloc((size_t)NSENT_P * SDIM * 2);
    unsigned short* sect_b = (unsigned short*)alloc((size_t)NSECT_P * TDIM * 2);
    unsigned short* w1t    = (unsigned short*)alloc((size_t)512 * 256 * 2);
    unsigned short* w2t    = (unsigned short*)alloc((size_t)512 * 512 * 2);
    unsigned short* fw1t   = (unsigned short*)alloc((size_t)2048 * 512 * 2);
    unsigned short* fw2t   = (unsigned short*)alloc((size_t)512 * 2048 * 2);
    float* Wr1 = (float*)alloc(512 * 8 * 4);
    float* el1 = (float*)alloc((size_t)NSENT_P * 8 * 4);
    float* er1 = (float*)alloc((size_t)NSECT_P * 8 * 4);
    float* el2 = (float*)alloc((size_t)NSECT_P * 8 * 4);
    float* er2 = (float*)alloc((size_t)NSECT_P * 8 * 4);
    unsigned short* fs1 = (unsigned short*)alloc((size_t)NSENT_P * 512 * 2);
    unsigned short* f2  = (unsigned short*)alloc((size_t)NSECT_P * 512 * 2);
    int* cnt1 = (int*)alloc((size_t)NSECT * 4);
    int* cnt2 = (int*)alloc((size_t)NSECT * 4);
    int* off1 = (int*)alloc((size_t)(NSECT + 1) * 4);
    int* off2 = (int*)alloc((size_t)(NSECT + 1) * 4);
    int* cur1 = (int*)alloc((size_t)NSECT * 4);
    int* cur2 = (int*)alloc((size_t)NSECT * 4);
    int* srcs1 = (int*)alloc((size_t)E_EDGES * 4);
    int* srcs2 = (int*)alloc((size_t)E_EDGES * 4);
    float* s2Sb = (float*)alloc((size_t)NSECT * 512 * 4);
    float* S2Sb = (float*)alloc((size_t)NSECT * 512 * 4);
    unsigned short* hb = (unsigned short*)alloc((size_t)NSECT_P * TDIM * 2);
    unsigned short* tb = fs1;   // alias: t[20096,2048] bf16 over fs1, fs1 dead by then

    // 1. fold (er1 weights) + weight transposes
    k_fold<<<16, 256, 0, stream>>>(W1_dst, ar1, Wr1);
    k_transpose<<<dim3(16, 8),  dim3(32, 8), 0, stream>>>(W1_src, w1t, 256, 512);
    k_transpose<<<dim3(16, 16), dim3(32, 8), 0, stream>>>(W2,     w2t, 512, 512);
    k_transpose<<<dim3(64, 16), dim3(32, 8), 0, stream>>>(ffn_w1, fw1t, 512, 2048);
    k_transpose<<<dim3(16, 64), dim3(32, 8), 0, stream>>>(ffn_w2, fw2t, 2048, 512);

    // 2. pure streaming converts + er1 projection
    k_convert_pad8<8><<<(int)(((long)NSENT_P * SDIM / 8 + 255) / 256), 256, 0, stream>>>(sent, sent_b, NSENT, NSENT_P);
    k_convert_pad8<9><<<(int)(((long)NSECT_P * TDIM / 8 + 255) / 256), 256, 0, stream>>>(sect, sect_b, NSECT, NSECT_P);
    k_proj8<<<NSECT / 4, 256, 0, stream>>>(sect, Wr1, er1, NSECT);

    // 3. feature GEMMs with fused attention-logit reductions
    k_gemm<0, 1, 4><<<(NSENT_P / 128) * 4, 256, 0, stream>>>(sent_b, w1t, fs1, nullptr, 512, 256, 0, 4, al1, el1, nullptr, nullptr);
    k_gemm<0, 2, 2><<<(NSECT_P / 64) * 4, 256, 0, stream>>>(sect_b, w2t, f2,  nullptr, 512, 512, 0, 4, al2, el2, ar2, er2);

    // 4. CSR build
    hipMemsetAsync(cnt1, 0, (size_t)NSECT * 4, stream);
    hipMemsetAsync(cnt2, 0, (size_t)NSECT * 4, stream);
    k_hist<<<E_EDGES / 256, 256, 0, stream>>>(s2S_dst, cnt1, E_EDGES);
    k_hist<<<E_EDGES / 256, 256, 0, stream>>>(S2S_dst, cnt2, E_EDGES);
    k_scan<<<1, 1024, 0, stream>>>(cnt1, off1, cur1, NSECT);
    k_scan<<<1, 1024, 0, stream>>>(cnt2, off2, cur2, NSECT);
    k_scatter<<<E_EDGES / 256, 256, 0, stream>>>(s2S_src, s2S_dst, cur1, srcs1, E_EDGES);
    k_scatter<<<E_EDGES / 256, 256, 0, stream>>>(S2S_src, S2S_dst, cur2, srcs2, E_EDGES);

    // 5. aggregation (softmax-weighted messages + bias + ELU)
    k_aggregate<<<NSECT / 4, 256, 0, stream>>>(fs1, el1, er1, b1, off1, srcs1, s2Sb, NSECT);
    k_aggregate<<<NSECT / 4, 256, 0, stream>>>(f2,  el2, er2, b2, off2, srcs2, S2Sb, NSECT);

    // 6. fusion gate + residual
    k_fusion<<<NSECT_P / 4, 256, 0, stream>>>(sect, s2Sb, S2Sb, fus_w, fus_b, hb);

    // 7. FFN
    k_gemm<1, 0, 2><<<(NSECT_P / 64) * (FFN / 128), 256, 0, stream>>>(hb, fw1t, tb, ffn_b1, FFN, 512, 0, FFN / 128, nullptr, nullptr, nullptr, nullptr);
    k_gemm<2, 0, 2><<<(NSECT_P / 64) * 4, 256, 0, stream>>>(tb, fw2t, d_out, ffn_b2, 512, FFN, NSECT, 4, nullptr, nullptr, nullptr, nullptr);
}

// Round 5
// 626.865 us; speedup vs baseline: 1.4578x; 1.0307x over previous
//
#include <hip/hip_runtime.h>

#define E_EDGES 320000
#define NSENT   100000
#define NSENT_P 100096
#define NSECT   20000
#define NSECT_P 20096
#define SDIM    256
#define TDIM    512
#define FFN     2048

typedef short bf16x8 __attribute__((ext_vector_type(8)));
typedef float f32x4  __attribute__((ext_vector_type(4)));

static __device__ __forceinline__ float bf2f(unsigned short u) {
    unsigned int i = ((unsigned int)u) << 16;
    float f; __builtin_memcpy(&f, &i, 4); return f;
}
static __device__ __forceinline__ unsigned short f2bf(float f) {
    unsigned int i; __builtin_memcpy(&i, &f, 4);
    unsigned int r = i + 0x7FFFu + ((i >> 16) & 1u);
    return (unsigned short)(r >> 16);
}

// async global->LDS, 16B per lane, dest = wave-uniform base + lane*16
static __device__ __forceinline__ void gload16(const unsigned short* g, unsigned short* l) {
    __builtin_amdgcn_global_load_lds(
        (const __attribute__((address_space(1))) unsigned int*)g,
        (__attribute__((address_space(3))) unsigned int*)l, 16, 0, 0);
}

// ---------------- fold: Wr1[k,h] = sum_d W1_dst[k, h*64+d] * ar1[h,d] ---
__global__ void k_fold(const float* __restrict__ W1d, const float* __restrict__ ar1,
                       float* __restrict__ Wr1)
{
    int t = blockIdx.x * 256 + threadIdx.x;
    if (t >= 4096) return;
    int k = t >> 3, h = t & 7;
    float s = 0.f;
    for (int d = 0; d < 64; ++d) s += W1d[k * 512 + h * 64 + d] * ar1[h * 64 + d];
    Wr1[t] = s;
}

// ---------------- transpose f32[R,C] -> bf16[C,R] -----------------------
__global__ void k_transpose(const float* __restrict__ in, unsigned short* __restrict__ out,
                            int R, int C)
{
    __shared__ float tile[32][33];
    int c0 = blockIdx.x * 32, r0 = blockIdx.y * 32;
    int tx = threadIdx.x, ty = threadIdx.y;
#pragma unroll
    for (int i = 0; i < 4; ++i)
        tile[ty + i * 8][tx] = in[(long)(r0 + ty + i * 8) * C + c0 + tx];
    __syncthreads();
#pragma unroll
    for (int i = 0; i < 4; ++i)
        out[(long)(c0 + ty + i * 8) * R + r0 + tx] = f2bf(tile[tx][ty + i * 8]);
}

// ---------------- convert f32 -> bf16, zero row padding, 8 elem/thread --
template<int LOGC>
__global__ __launch_bounds__(256)
void k_convert_pad8(const float* __restrict__ X, unsigned short* __restrict__ out,
                    int Nreal, int Npad)
{
    long i8 = (((long)blockIdx.x * 256) + threadIdx.x) * 8;
    if (i8 >= ((long)Npad << LOGC)) return;
    int row = (int)(i8 >> LOGC);
    uint4 o;
    if (row < Nreal) {
        float4 v0 = *(const float4*)(X + i8);
        float4 v1 = *(const float4*)(X + i8 + 4);
        o.x = ((unsigned int)f2bf(v0.x)) | (((unsigned int)f2bf(v0.y)) << 16);
        o.y = ((unsigned int)f2bf(v0.z)) | (((unsigned int)f2bf(v0.w)) << 16);
        o.z = ((unsigned int)f2bf(v1.x)) | (((unsigned int)f2bf(v1.y)) << 16);
        o.w = ((unsigned int)f2bf(v1.z)) | (((unsigned int)f2bf(v1.w)) << 16);
    } else { o = make_uint4(0u, 0u, 0u, 0u); }
    *(uint4*)(out + i8) = o;
}

// ------- er1 projection: out[N,8] = X[N,512] @ Wf[512,8], wave per row --
__global__ __launch_bounds__(256)
void k_proj8(const float* __restrict__ X, const float* __restrict__ Wf,
             float* __restrict__ out, int Nrows)
{
    int lane = threadIdx.x & 63;
    int row  = blockIdx.x * 4 + (threadIdx.x >> 6);
    f32x4 w[16];
    const f32x4* wp = (const f32x4*)(Wf + lane * 64);
#pragma unroll
    for (int i = 0; i < 16; ++i) w[i] = wp[i];
    if (row >= Nrows) return;
    float4 x0 = *(const float4*)(X + (long)row * 512 + lane * 8);
    float4 x1 = *(const float4*)(X + (long)row * 512 + lane * 8 + 4);
    float xs[8] = {x0.x, x0.y, x0.z, x0.w, x1.x, x1.y, x1.z, x1.w};
    float p[8] = {};
#pragma unroll
    for (int j = 0; j < 8; ++j) {
        f32x4 wa = w[j * 2], wb = w[j * 2 + 1];
        p[0] += xs[j] * wa[0]; p[1] += xs[j] * wa[1];
        p[2] += xs[j] * wa[2]; p[3] += xs[j] * wa[3];
        p[4] += xs[j] * wb[0]; p[5] += xs[j] * wb[1];
        p[6] += xs[j] * wb[2]; p[7] += xs[j] * wb[3];
    }
#pragma unroll
    for (int s = 1; s < 64; s <<= 1)
#pragma unroll
        for (int h = 0; h < 8; ++h) p[h] += __shfl_xor(p[h], s);
    if (lane == 0) {
        *(float4*)(out + (long)row * 8)     = make_float4(p[0], p[1], p[2], p[3]);
        *(float4*)(out + (long)row * 8 + 4) = make_float4(p[4], p[5], p[6], p[7]);
    }
}

// ---------------- MFMA GEMM: C[M,N] = A[M,K]bf16 @ BT[N,K]bf16 ----------
// Tile: (32*MT) x 128, 4 waves as 2x2, per-wave acc[MT][4] of 16x16.
// Staging: global_load_lds width=16, linear LDS (no padding), wave-uniform
// LDS base + per-lane global src. 1-D grid, N-fastest, bijective XCD swizzle.
// EPI 0: store bf16 | 1: +bias, relu, bf16 | 2: +bias, f32 (row<Mreal)
// NATT: 0/1/2 head-dot reductions from the f32 accumulator.
template<int EPI, int NATT, int MT>
__global__ __launch_bounds__(256)
void k_gemm(const unsigned short* __restrict__ A, const unsigned short* __restrict__ BT,
            void* __restrict__ C, const float* __restrict__ bias,
            int N, int K, int Mreal, int ntx,
            const float* __restrict__ av0, float* __restrict__ eo0,
            const float* __restrict__ av1, float* __restrict__ eo1)
{
    __shared__ unsigned short a_s[MT * 32][32];
    __shared__ unsigned short b_s[128][32];
    const int tid  = threadIdx.x;
    const int lane = tid & 63;
    const int wid  = tid >> 6;
    const int wr   = (wid >> 1) * (16 * MT);
    const int wc   = (wid & 1) * 64;

    // bijective XCD-contiguous remap: physical bid -> logical tile wgid
    const int nwg = gridDim.x;
    const int bid = blockIdx.x;
    const int q = nwg >> 3, r = nwg & 7;
    const int xcd = bid & 7;
    const int wgid = (xcd < r ? xcd * (q + 1) : r * (q + 1) + (xcd - r) * q) + (bid >> 3);
    const int row0 = (wgid / ntx) * (32 * MT);
    const int col0 = (wgid % ntx) * 128;

    // staging: chunk = 16 rows x 32 cols bf16 = 1 KB = one gload16 per wave
    // lane l covers row 16c + l/4, col-shorts (l&3)*8
    const int l4 = lane >> 2;
    const int lc = (lane & 3) * 8;

    const unsigned short* gA0;
    const unsigned short* gA1 = nullptr;
    unsigned short* lA0;
    unsigned short* lA1 = nullptr;
    if (MT == 2) {                       // 4 A-chunks, one per wave
        gA0 = A + (long)(row0 + 16 * wid + l4) * K + lc;
        lA0 = &a_s[16 * wid][0];
    } else {                             // 8 A-chunks, two per wave
        gA0 = A + (long)(row0 + 16 * (2 * wid) + l4) * K + lc;
        gA1 = A + (long)(row0 + 16 * (2 * wid + 1) + l4) * K + lc;
        lA0 = &a_s[16 * (2 * wid)][0];
        lA1 = &a_s[16 * (2 * wid + 1)][0];
    }
    const unsigned short* gB0 = BT + (long)(col0 + 16 * (2 * wid) + l4) * K + lc;
    const unsigned short* gB1 = BT + (long)(col0 + 16 * (2 * wid + 1) + l4) * K + lc;
    unsigned short* lB0 = &b_s[16 * (2 * wid)][0];
    unsigned short* lB1 = &b_s[16 * (2 * wid + 1)][0];

    f32x4 acc[MT][4] = {};

    for (int k0 = 0; k0 < K; k0 += 32) {
        __syncthreads();                 // previous tile's reads complete
        gload16(gA0 + k0, lA0);
        if (MT == 4) gload16(gA1 + k0, lA1);
        gload16(gB0 + k0, lB0);
        gload16(gB1 + k0, lB1);
        __syncthreads();                 // drains vmcnt -> LDS populated
        bf16x8 af[MT], bfr[4];
#pragma unroll
        for (int m = 0; m < MT; ++m)
            af[m] = *(const bf16x8*)&a_s[wr + m * 16 + (lane & 15)][8 * (lane >> 4)];
#pragma unroll
        for (int n = 0; n < 4; ++n)
            bfr[n] = *(const bf16x8*)&b_s[wc + n * 16 + (lane & 15)][8 * (lane >> 4)];
#pragma unroll
        for (int m = 0; m < MT; ++m)
#pragma unroll
            for (int n = 0; n < 4; ++n)
                acc[m][n] = __builtin_amdgcn_mfma_f32_16x16x32_bf16(af[m], bfr[n], acc[m][n], 0, 0, 0);
    }

#pragma unroll
    for (int m = 0; m < MT; ++m) {
        int row_t = wr + m * 16 + ((lane >> 4) << 2);
#pragma unroll
        for (int n = 0; n < 4; ++n) {
            int col = col0 + wc + n * 16 + (lane & 15);
#pragma unroll
            for (int r2 = 0; r2 < 4; ++r2) {
                int row = row0 + row_t + r2;
                float v = acc[m][n][r2];
                if (EPI >= 1) v += bias[col];
                if (EPI == 1) v = fmaxf(v, 0.f);
                if (EPI <= 1) {
                    ((unsigned short*)C)[(long)row * N + col] = f2bf(v);
                } else {
                    if (row < Mreal) ((float*)C)[(long)row * N + col] = v;
                }
            }
        }
    }

    if (NATT >= 1) {
        // this wave's 64-column stripe is exactly one head
        int hw = (col0 + wc) >> 6;
        float av0r[4], av1r[4];
#pragma unroll
        for (int n = 0; n < 4; ++n) {
            int c = col0 + wc + n * 16 + (lane & 15);
            av0r[n] = av0[c];
            if (NATT == 2) av1r[n] = av1[c];
        }
        float red0[MT * 4], red1[MT * 4];
#pragma unroll
        for (int m = 0; m < MT; ++m)
#pragma unroll
            for (int r2 = 0; r2 < 4; ++r2) {
                red0[m * 4 + r2] = acc[m][0][r2] * av0r[0] + acc[m][1][r2] * av0r[1]
                                 + acc[m][2][r2] * av0r[2] + acc[m][3][r2] * av0r[3];
                if (NATT == 2)
                    red1[m * 4 + r2] = acc[m][0][r2] * av1r[0] + acc[m][1][r2] * av1r[1]
                                     + acc[m][2][r2] * av1r[2] + acc[m][3][r2] * av1r[3];
            }
#pragma unroll
        for (int s = 1; s < 16; s <<= 1)
#pragma unroll
            for (int j = 0; j < MT * 4; ++j) {
                red0[j] += __shfl_xor(red0[j], s);
                if (NATT == 2) red1[j] += __shfl_xor(red1[j], s);
            }
        if ((lane & 15) == 0) {
#pragma unroll
            for (int m = 0; m < MT; ++m)
#pragma unroll
                for (int r2 = 0; r2 < 4; ++r2) {
                    int row = row0 + wr + m * 16 + ((lane >> 4) << 2) + r2;
                    eo0[row * 8 + hw] = red0[m * 4 + r2];
                    if (NATT == 2) eo1[row * 8 + hw] = red1[m * 4 + r2];
                }
        }
    }
}

// ---------------- CSR build ---------------------------------------------
__global__ void k_hist(const int* __restrict__ dst, int* __restrict__ cnt, int E)
{
    int i = blockIdx.x * 256 + threadIdx.x;
    if (i < E) atomicAdd(&cnt[dst[i]], 1);
}

__global__ void k_scan(const int* __restrict__ cnt, int* __restrict__ off,
                       int* __restrict__ cur, int Nseg)
{
    __shared__ int partial[1024];
    int t = threadIdx.x;
    int chunk = (Nseg + 1023) / 1024;
    int b = t * chunk;
    int e_ = b + chunk; if (e_ > Nseg) e_ = Nseg; if (b > Nseg) b = Nseg;
    int s = 0;
    for (int i = b; i < e_; ++i) s += cnt[i];
    partial[t] = s;
    __syncthreads();
    for (int d = 1; d < 1024; d <<= 1) {
        int v = partial[t];
        int w = (t >= d) ? partial[t - d] : 0;
        __syncthreads();
        partial[t] = v + w;
        __syncthreads();
    }
    int run = (t == 0) ? 0 : partial[t - 1];
    for (int i = b; i < e_; ++i) { off[i] = run; cur[i] = run; run += cnt[i]; }
    if (t == 1023) off[Nseg] = partial[1023];
}

__global__ void k_scatter(const int* __restrict__ src, const int* __restrict__ dst,
                          int* __restrict__ cur, int* __restrict__ srcs, int E)
{
    int i = blockIdx.x * 256 + threadIdx.x;
    if (i < E) {
        int p = atomicAdd(&cur[dst[i]], 1);
        srcs[p] = src[i];
    }
}

// ---------------- GAT aggregation: one wave per dst segment -------------
__global__ __launch_bounds__(256)
void k_aggregate(const unsigned short* __restrict__ fs, const float* __restrict__ el,
                 const float* __restrict__ er, const float* __restrict__ bias,
                 const int* __restrict__ off, const int* __restrict__ srcs,
                 float* __restrict__ out, int Ndst)
{
    int n = blockIdx.x * 4 + (threadIdx.x >> 6);
    if (n >= Ndst) return;
    int lane = threadIdx.x & 63;
    int h8 = lane & 7;
    int beg = off[n], end = off[n + 1];
    float er_h = er[n * 8 + h8];

    float mx = -3.0e38f;
    for (int p = beg + (lane >> 3); p < end; p += 8) {
        int s = srcs[p];
        float e = el[s * 8 + h8] + er_h;
        e = (e >= 0.f) ? e : 0.2f * e;
        mx = fmaxf(mx, e);
    }
    mx = fmaxf(mx, __shfl_xor(mx, 8));
    mx = fmaxf(mx, __shfl_xor(mx, 16));
    mx = fmaxf(mx, __shfl_xor(mx, 32));

    float dsum = 0.f;
    for (int p = beg + (lane >> 3); p < end; p += 8) {
        int s = srcs[p];
        float e = el[s * 8 + h8] + er_h;
        e = (e >= 0.f) ? e : 0.2f * e;
        dsum += __expf(e - mx);
    }
    dsum += __shfl_xor(dsum, 8);
    dsum += __shfl_xor(dsum, 16);
    dsum += __shfl_xor(dsum, 32);

    int hc = lane >> 3;                 // head owned by this lane's 8 dims
    float mx_c   = __shfl(mx, hc);
    float dsum_c = __shfl(dsum, hc);
    float er_c   = er[n * 8 + hc];

    float a0=0,a1=0,a2=0,a3=0,a4=0,a5=0,a6=0,a7=0;
    const unsigned short* fsl = fs + lane * 8;
    for (int p = beg; p < end; ++p) {
        int s = srcs[p];
        float e = el[s * 8 + hc] + er_c;
        e = (e >= 0.f) ? e : 0.2f * e;
        float w = __expf(e - mx_c);
        uint4 v = *(const uint4*)(fsl + (long)s * 512);
        a0 += w * bf2f((unsigned short)(v.x & 0xFFFF));
        a1 += w * bf2f((unsigned short)(v.x >> 16));
        a2 += w * bf2f((unsigned short)(v.y & 0xFFFF));
        a3 += w * bf2f((unsigned short)(v.y >> 16));
        a4 += w * bf2f((unsigned short)(v.z & 0xFFFF));
        a5 += w * bf2f((unsigned short)(v.z >> 16));
        a6 += w * bf2f((unsigned short)(v.w & 0xFFFF));
        a7 += w * bf2f((unsigned short)(v.w >> 16));
    }
    float inv = 1.f / fmaxf(dsum_c, 1e-9f);
    const float* bp = bias + lane * 8;
    float o[8] = { a0*inv + bp[0], a1*inv + bp[1], a2*inv + bp[2], a3*inv + bp[3],
                   a4*inv + bp[4], a5*inv + bp[5], a6*inv + bp[6], a7*inv + bp[7] };
#pragma unroll
    for (int j = 0; j < 8; ++j) o[j] = (o[j] > 0.f) ? o[j] : (__expf(o[j]) - 1.f);
    float4 w0 = make_float4(o[0], o[1], o[2], o[3]);
    float4 w1 = make_float4(o[4], o[5], o[6], o[7]);
    *(float4*)(out + (long)n * 512 + lane * 8)     = w0;
    *(float4*)(out + (long)n * 512 + lane * 8 + 4) = w1;
}

// ---------------- fusion gate + residual -> bf16 h ----------------------
__global__ __launch_bounds__(256)
void k_fusion(const float* __restrict__ sect, const float* __restrict__ s2S,
              const float* __restrict__ S2S, const float* __restrict__ fw,
              const float* __restrict__ fb, unsigned short* __restrict__ hout)
{
    int n = blockIdx.x * 4 + (threadIdx.x >> 6);
    if (n >= NSECT_P) return;
    int lane = threadIdx.x & 63;
    unsigned short* op = hout + (long)n * TDIM + lane * 8;
    if (n >= NSECT) {
        uint4 z = make_uint4(0u, 0u, 0u, 0u);
        *(uint4*)op = z;
        return;
    }
    long base = (long)n * TDIM + lane * 8;
    float4 p0 = *(const float4*)(s2S + base);
    float4 p1 = *(const float4*)(s2S + base + 4);
    float4 q0 = *(const float4*)(S2S + base);
    float4 q1 = *(const float4*)(S2S + base + 4);
    float4 wa0 = *(const float4*)(fw + lane * 8);
    float4 wa1 = *(const float4*)(fw + lane * 8 + 4);
    float4 wb0 = *(const float4*)(fw + 512 + lane * 8);
    float4 wb1 = *(const float4*)(fw + 512 + lane * 8 + 4);
    float part = p0.x*wa0.x + p0.y*wa0.y + p0.z*wa0.z + p0.w*wa0.w
               + p1.x*wa1.x + p1.y*wa1.y + p1.z*wa1.z + p1.w*wa1.w
               + q0.x*wb0.x + q0.y*wb0.y + q0.z*wb0.z + q0.w*wb0.w
               + q1.x*wb1.x + q1.y*wb1.y + q1.z*wb1.z + q1.w*wb1.w;
#pragma unroll
    for (int s = 1; s < 64; s <<= 1) part += __shfl_xor(part, s);
    float z = 1.f / (1.f + __expf(-(part + fb[0])));
    float4 r0 = *(const float4*)(sect + base);
    float4 r1 = *(const float4*)(sect + base + 4);
    float h[8];
    h[0] = r0.x + z * p0.x + (1.f - z) * q0.x;
    h[1] = r0.y + z * p0.y + (1.f - z) * q0.y;
    h[2] = r0.z + z * p0.z + (1.f - z) * q0.z;
    h[3] = r0.w + z * p0.w + (1.f - z) * q0.w;
    h[4] = r1.x + z * p1.x + (1.f - z) * q1.x;
    h[5] = r1.y + z * p1.y + (1.f - z) * q1.y;
    h[6] = r1.z + z * p1.z + (1.f - z) * q1.z;
    h[7] = r1.w + z * p1.w + (1.f - z) * q1.w;
    uint4 o;
    o.x = ((unsigned int)f2bf(h[0])) | (((unsigned int)f2bf(h[1])) << 16);
    o.y = ((unsigned int)f2bf(h[2])) | (((unsigned int)f2bf(h[3])) << 16);
    o.z = ((unsigned int)f2bf(h[4])) | (((unsigned int)f2bf(h[5])) << 16);
    o.w = ((unsigned int)f2bf(h[6])) | (((unsigned int)f2bf(h[7])) << 16);
    *(uint4*)op = o;
}

// ------------------------------------------------------------------------
extern "C" void kernel_launch(void* const* d_in, const int* in_sizes, int n_in,
                              void* d_out, int out_size, void* d_ws, size_t ws_size,
                              hipStream_t stream)
{
    (void)in_sizes; (void)n_in; (void)out_size; (void)ws_size;
    const float* sent    = (const float*)d_in[0];
    const float* sect    = (const float*)d_in[1];
    const int*   s2S_src = (const int*)d_in[2];
    const int*   s2S_dst = (const int*)d_in[3];
    const int*   S2S_src = (const int*)d_in[4];
    const int*   S2S_dst = (const int*)d_in[5];
    const float* W1_src  = (const float*)d_in[6];
    const float* W1_dst  = (const float*)d_in[7];
    const float* al1     = (const float*)d_in[8];
    const float* ar1     = (const float*)d_in[9];
    const float* b1      = (const float*)d_in[10];
    const float* W2      = (const float*)d_in[11];
    const float* al2     = (const float*)d_in[12];
    const float* ar2     = (const float*)d_in[13];
    const float* b2      = (const float*)d_in[14];
    const float* fus_w   = (const float*)d_in[15];
    const float* fus_b   = (const float*)d_in[16];
    const float* ffn_w1  = (const float*)d_in[17];
    const float* ffn_b1  = (const float*)d_in[18];
    const float* ffn_w2  = (const float*)d_in[19];
    const float* ffn_b2  = (const float*)d_in[20];

    char* ws = (char*)d_ws;
    size_t curo = 0;
    auto alloc = [&](size_t sz) -> void* {
        void* p = ws + curo; curo += (sz + 255) & ~(size_t)255; return p;
    };

    unsigned short* sent_b = (unsigned short*)alloc((size_t)NSENT_P * SDIM * 2);
    unsigned short* sect_b = (unsigned short*)alloc((size_t)NSECT_P * TDIM * 2);
    unsigned short* w1t    = (unsigned short*)alloc((size_t)512 * 256 * 2);
    unsigned short* w2t    = (unsigned short*)alloc((size_t)512 * 512 * 2);
    unsigned short* fw1t   = (unsigned short*)alloc((size_t)2048 * 512 * 2);
    unsigned short* fw2t   = (unsigned short*)alloc((size_t)512 * 2048 * 2);
    float* Wr1 = (float*)alloc(512 * 8 * 4);
    float* el1 = (float*)alloc((size_t)NSENT_P * 8 * 4);
    float* er1 = (float*)alloc((size_t)NSECT_P * 8 * 4);
    float* el2 = (float*)alloc((size_t)NSECT_P * 8 * 4);
    float* er2 = (float*)alloc((size_t)NSECT_P * 8 * 4);
    unsigned short* fs1 = (unsigned short*)alloc((size_t)NSENT_P * 512 * 2);
    unsigned short* f2  = (unsigned short*)alloc((size_t)NSECT_P * 512 * 2);
    int* cnt1 = (int*)alloc((size_t)NSECT * 4);
    int* cnt2 = (int*)alloc((size_t)NSECT * 4);
    int* off1 = (int*)alloc((size_t)(NSECT + 1) * 4);
    int* off2 = (int*)alloc((size_t)(NSECT + 1) * 4);
    int* cur1 = (int*)alloc((size_t)NSECT * 4);
    int* cur2 = (int*)alloc((size_t)NSECT * 4);
    int* srcs1 = (int*)alloc((size_t)E_EDGES * 4);
    int* srcs2 = (int*)alloc((size_t)E_EDGES * 4);
    float* s2Sb = (float*)alloc((size_t)NSECT * 512 * 4);
    float* S2Sb = (float*)alloc((size_t)NSECT * 512 * 4);
    unsigned short* hb = (unsigned short*)alloc((size_t)NSECT_P * TDIM * 2);
    unsigned short* tb = fs1;   // alias: t[20096,2048] bf16 over fs1, fs1 dead by then

    // 1. fold (er1 weights) + weight transposes
    k_fold<<<16, 256, 0, stream>>>(W1_dst, ar1, Wr1);
    k_transpose<<<dim3(16, 8),  dim3(32, 8), 0, stream>>>(W1_src, w1t, 256, 512);
    k_transpose<<<dim3(16, 16), dim3(32, 8), 0, stream>>>(W2,     w2t, 512, 512);
    k_transpose<<<dim3(64, 16), dim3(32, 8), 0, stream>>>(ffn_w1, fw1t, 512, 2048);
    k_transpose<<<dim3(16, 64), dim3(32, 8), 0, stream>>>(ffn_w2, fw2t, 2048, 512);

    // 2. pure streaming converts + er1 projection
    k_convert_pad8<8><<<(int)(((long)NSENT_P * SDIM / 8 + 255) / 256), 256, 0, stream>>>(sent, sent_b, NSENT, NSENT_P);
    k_convert_pad8<9><<<(int)(((long)NSECT_P * TDIM / 8 + 255) / 256), 256, 0, stream>>>(sect, sect_b, NSECT, NSECT_P);
    k_proj8<<<NSECT / 4, 256, 0, stream>>>(sect, Wr1, er1, NSECT);

    // 3. feature GEMMs with fused attention-logit reductions
    k_gemm<0, 1, 4><<<(NSENT_P / 128) * 4, 256, 0, stream>>>(sent_b, w1t, fs1, nullptr, 512, 256, 0, 4, al1, el1, nullptr, nullptr);
    k_gemm<0, 2, 2><<<(NSECT_P / 64) * 4, 256, 0, stream>>>(sect_b, w2t, f2,  nullptr, 512, 512, 0, 4, al2, el2, ar2, er2);

    // 4. CSR build
    hipMemsetAsync(cnt1, 0, (size_t)NSECT * 4, stream);
    hipMemsetAsync(cnt2, 0, (size_t)NSECT * 4, stream);
    k_hist<<<E_EDGES / 256, 256, 0, stream>>>(s2S_dst, cnt1, E_EDGES);
    k_hist<<<E_EDGES / 256, 256, 0, stream>>>(S2S_dst, cnt2, E_EDGES);
    k_scan<<<1, 1024, 0, stream>>>(cnt1, off1, cur1, NSECT);
    k_scan<<<1, 1024, 0, stream>>>(cnt2, off2, cur2, NSECT);
    k_scatter<<<E_EDGES / 256, 256, 0, stream>>>(s2S_src, s2S_dst, cur1, srcs1, E_EDGES);
    k_scatter<<<E_EDGES / 256, 256, 0, stream>>>(S2S_src, S2S_dst, cur2, srcs2, E_EDGES);

    // 5. aggregation (softmax-weighted messages + bias + ELU)
    k_aggregate<<<NSECT / 4, 256, 0, stream>>>(fs1, el1, er1, b1, off1, srcs1, s2Sb, NSECT);
    k_aggregate<<<NSECT / 4, 256, 0, stream>>>(f2,  el2, er2, b2, off2, srcs2, S2Sb, NSECT);

    // 6. fusion gate + residual
    k_fusion<<<NSECT_P / 4, 256, 0, stream>>>(sect, s2Sb, S2Sb, fus_w, fus_b, hb);

    // 7. FFN
    k_gemm<1, 0, 4><<<(NSECT_P / 128) * (FFN / 128), 256, 0, stream>>>(hb, fw1t, tb, ffn_b1, FFN, 512, 0, FFN / 128, nullptr, nullptr, nullptr, nullptr);
    k_gemm<2, 0, 2><<<(NSECT_P / 64) * 4, 256, 0, stream>>>(tb, fw2t, d_out, ffn_b2, 512, FFN, NSECT, 4, nullptr, nullptr, nullptr, nullptr);
}